// Round 12
// baseline (365.517 us; speedup 1.0000x reference)
//
#include <hip/hip_runtime.h>
#include <hip/hip_bf16.h>
#include <math.h>

#define BB 2
#define SS 2048
#define HID 2048
#define NH 32
#define NKV 8
#define DD 128

typedef unsigned short u16;
typedef __attribute__((ext_vector_type(8))) short short8;
typedef __attribute__((ext_vector_type(4))) float f32x4;
typedef __attribute__((ext_vector_type(16))) float f32x16;
typedef __attribute__((ext_vector_type(4))) unsigned short us4;

__device__ __forceinline__ u16 f2bf(float f) {
    unsigned int u = __float_as_uint(f);
    u += 0x7fff + ((u >> 16) & 1);
    return (u16)(u >> 16);
}
__device__ __forceinline__ float bf2f(u16 h) {
    return __uint_as_float(((unsigned int)h) << 16);
}

#define GLOAD16(gp, lp) __builtin_amdgcn_global_load_lds(                      \
    (const __attribute__((address_space(1))) void*)(gp),                       \
    (__attribute__((address_space(3))) void*)(lp), 16, 0, 0)

#define MFMA32(a, b, c) __builtin_amdgcn_mfma_f32_32x32x16_bf16(a, b, c, 0, 0, 0)
#define MFMA16(a, b, c) __builtin_amdgcn_mfma_f32_16x16x32_bf16(a, b, c, 0, 0, 0)

// ---------------------------------------------------------------------------
// cvt: fp32 -> bf16 elementwise (8 elems/thread)
// ---------------------------------------------------------------------------
__global__ __launch_bounds__(256) void cvt_k(const float* __restrict__ in,
                                             u16* __restrict__ out, int n8)
{
    int i = blockIdx.x * 256 + threadIdx.x;
    if (i >= n8) return;
    f32x4 a = ((const f32x4*)in)[i * 2];
    f32x4 b = ((const f32x4*)in)[i * 2 + 1];
    short8 o;
#pragma unroll
    for (int j = 0; j < 4; ++j) { o[j] = (short)f2bf(a[j]); o[4 + j] = (short)f2bf(b[j]); }
    ((short8*)out)[i] = o;
}

// ---------------------------------------------------------------------------
// transpose + convert: fp32 in[R][C] -> bf16 out[C][R]. 32x32 tiles.
// ---------------------------------------------------------------------------
__global__ __launch_bounds__(256) void tw_k(const float* __restrict__ in,
                                            u16* __restrict__ out, int R, int C)
{
    __shared__ float t[32][33];
    const int tc = blockIdx.x * 32, tr = blockIdx.y * 32;
    const int r = threadIdx.x >> 3, c4 = (threadIdx.x & 7) * 4;
    f32x4 v = *(const f32x4*)(in + (size_t)(tr + r) * C + tc + c4);
#pragma unroll
    for (int j = 0; j < 4; ++j) t[r][c4 + j] = v[j];
    __syncthreads();
    us4 o;
#pragma unroll
    for (int j = 0; j < 4; ++j) o[j] = f2bf(t[c4 + j][r]);
    *(us4*)(out + (size_t)(tc + r) * R + tr + c4) = o;
}

// ---------------------------------------------------------------------------
// V transpose (fallback-path only): Vb (B,S,HKV,D) -> Vt (B,HKV,D,S).
// ---------------------------------------------------------------------------
__global__ __launch_bounds__(256) void vtr_k(const u16* __restrict__ Vb,
                                             u16* __restrict__ Vt)
{
    __shared__ u16 t[64][72];
    const int s0 = blockIdx.x * 64, d0 = blockIdx.y * 64;
    const int b = blockIdx.z >> 3, hkv = blockIdx.z & 7;
    const int tid = threadIdx.x;
    const int rr = tid >> 3, cc = (tid & 7) * 8;
#pragma unroll
    for (int it = 0; it < 2; ++it) {
        int row = rr + it * 32;
        short8 v = *(const short8*)(Vb + ((size_t)(b * SS + s0 + row) * NKV + hkv) * DD + d0 + cc);
#pragma unroll
        for (int j = 0; j < 8; ++j) t[row][cc + j] = (u16)v[j];
    }
    __syncthreads();
#pragma unroll
    for (int it = 0; it < 2; ++it) {
        int dr = rr + it * 32;
        short8 o;
#pragma unroll
        for (int j = 0; j < 8; ++j) o[j] = (short)t[cc + j][dr];
        *(short8*)(Vt + ((size_t)(b * NKV + hkv) * DD + d0 + dr) * SS + s0 + cc) = o;
    }
}

#define PHASE_END() do {                                       \
    asm volatile("s_waitcnt lgkmcnt(0)" ::: "memory");         \
    __builtin_amdgcn_sched_barrier(0);                         \
    __builtin_amdgcn_s_barrier();                              \
  } while (0)

// ---------------------------------------------------------------------------
// Deep-pipeline GEMM, 256x128 tile, BK=64, 8 waves (4M x 2N, 64x64/wave).
// LDS: A 4 x (128x64) half-tile slots + B 2 x (128x64) tile slots = 96KB.
// 4 phases/tile: p0 {read c0 frags, 8 MFMA}, p1 {read c1 frags, 8 MFMA},
// p2 {8 MFMA, issue A-stage T+2}, p3 {8 MFMA, issue B-stage T+2, vmcnt(6)}.
// All reads of a slot in p0/p1; its restage issued >=1 barrier later ->
// race-free. Counted vmcnt leaves only T+2's 6 loads in flight.
// OPROJ=false: QKV routing epilogue (Q / K / V-transposed-into-Vt).
// OPROJ=true : plain f32 C[M,N] epilogue.
// Grid: 8 XCDs x (2 M-rows x N-cols); QKV 768 (3 exact rounds), O 256 (1).
// ---------------------------------------------------------------------------
template<bool OPROJ>
__global__ __launch_bounds__(512, 2) void gemmdp_k(const u16* __restrict__ A,
                                                   const u16* __restrict__ Bt,
                                                   void* __restrict__ C0,
                                                   u16* __restrict__ Kb_,
                                                   u16* __restrict__ Vt_,
                                                   int K, int N)
{
    const int k8 = blockIdx.x & 7;
    const int j  = (int)blockIdx.x >> 3;
    const int by = k8 * 2 + (j & 1);
    const int bx = j >> 1;
    const int m0 = by * 256, n0 = bx * 128;

    __shared__ u16 Asl[4][128 * 64];
    __shared__ u16 Bsl[2][128 * 64];

    const int tid = threadIdx.x;
    const int w = tid >> 6, lane = tid & 63;
    const int wm = w >> 1, wn = w & 1;
    const int lo = lane & 15, hi = lane >> 4;
    const int ah  = wm >> 1;            // A half-slot this wave reads
    const int ar0 = (wm & 1) * 64;      // A local row base
    const int br0 = wn * 64;            // B row base

    const int srow8 = lane >> 3;
    const int skk = ((lane & 7) ^ srow8) * 8;
    const u16* Asrc = A + (size_t)(m0 + w * 32 + srow8) * K + skk;
    const u16* Bsrc = Bt + (size_t)(n0 + w * 16 + srow8) * K + skk;
    const int wsh = w >> 2;             // staging half
    const int war = (w & 3) * 32;       // staging local row base

#define SAD(P, kof) do {                                                              \
    _Pragma("unroll") for (int g = 0; g < 4; ++g)                                     \
      GLOAD16(Asrc + (size_t)(g * 8) * K + (kof), &Asl[(P) * 2 + wsh][(war + g * 8) * 64]); \
  } while (0)
#define SBD(P, kof) do {                                                              \
    _Pragma("unroll") for (int g = 0; g < 2; ++g)                                     \
      GLOAD16(Bsrc + (size_t)(g * 8) * K + (kof), &Bsl[P][(w * 16 + g * 8) * 64]);    \
  } while (0)

    f32x4 acc[4][4] = {};
    const int nt = K >> 6;

    // ---- prologue: stage tiles 0 and 1 ----
    SAD(0, 0);  SBD(0, 0);
    SAD(1, 64); SBD(1, 64);
    asm volatile("s_waitcnt vmcnt(6)" ::: "memory");   // tile0 landed
    __builtin_amdgcn_s_barrier();

#define TILEDP(P, T) do {                                                             \
    const u16* Apan = Asl[(P) * 2 + ah];                                              \
    const u16* Bpan = Bsl[P];                                                         \
    short8 afr[2][4], bfr[2][4];                                                      \
    /* p0: read c0 frags; MFMA c0 x j01 */                                            \
    _Pragma("unroll") for (int i = 0; i < 4; ++i)                                     \
      afr[0][i] = *(const short8*)&Apan[(ar0 + i * 16 + lo) * 64 + ((hi ^ (lo & 7)) * 8)]; \
    _Pragma("unroll") for (int jj = 0; jj < 4; ++jj)                                  \
      bfr[0][jj] = *(const short8*)&Bpan[(br0 + jj * 16 + lo) * 64 + ((hi ^ (lo & 7)) * 8)]; \
    __builtin_amdgcn_s_setprio(1);                                                    \
    _Pragma("unroll") for (int i = 0; i < 4; ++i) {                                   \
      acc[i][0] = MFMA16(afr[0][i], bfr[0][0], acc[i][0]);                            \
      acc[i][1] = MFMA16(afr[0][i], bfr[0][1], acc[i][1]);                            \
    }                                                                                 \
    __builtin_amdgcn_s_setprio(0);                                                    \
    PHASE_END();                                                                      \
    /* p1: read c1 frags; MFMA c0 x j23 */                                            \
    _Pragma("unroll") for (int i = 0; i < 4; ++i)                                     \
      afr[1][i] = *(const short8*)&Apan[(ar0 + i * 16 + lo) * 64 + (((4 + hi) ^ (lo & 7)) * 8)]; \
    _Pragma("unroll") for (int jj = 0; jj < 4; ++jj)                                  \
      bfr[1][jj] = *(const short8*)&Bpan[(br0 + jj * 16 + lo) * 64 + (((4 + hi) ^ (lo & 7)) * 8)]; \
    __builtin_amdgcn_s_setprio(1);                                                    \
    _Pragma("unroll") for (int i = 0; i < 4; ++i) {                                   \
      acc[i][2] = MFMA16(afr[0][i], bfr[0][2], acc[i][2]);                            \
      acc[i][3] = MFMA16(afr[0][i], bfr[0][3], acc[i][3]);                            \
    }                                                                                 \
    __builtin_amdgcn_s_setprio(0);                                                    \
    PHASE_END();                                                                      \
    /* p2: MFMA c1 x j01; issue A-stage T+2 */                                        \
    __builtin_amdgcn_s_setprio(1);                                                    \
    _Pragma("unroll") for (int i = 0; i < 4; ++i) {                                   \
      acc[i][0] = MFMA16(afr[1][i], bfr[1][0], acc[i][0]);                            \
      acc[i][1] = MFMA16(afr[1][i], bfr[1][1], acc[i][1]);                            \
    }                                                                                 \
    __builtin_amdgcn_s_setprio(0);                                                    \
    if ((T) + 2 < nt) SAD(P, ((T) + 2) * 64);                                         \
    PHASE_END();                                                                      \
    /* p3: MFMA c1 x j23; issue B-stage T+2; counted vmcnt */                         \
    __builtin_amdgcn_s_setprio(1);                                                    \
    _Pragma("unroll") for (int i = 0; i < 4; ++i) {                                   \
      acc[i][2] = MFMA16(afr[1][i], bfr[1][2], acc[i][2]);                            \
      acc[i][3] = MFMA16(afr[1][i], bfr[1][3], acc[i][3]);                            \
    }                                                                                 \
    __builtin_amdgcn_s_setprio(0);                                                    \
    if ((T) + 2 < nt) {                                                               \
      SBD(P, ((T) + 2) * 64);                                                         \
      asm volatile("s_waitcnt vmcnt(6)" ::: "memory");                                \
    } else {                                                                          \
      asm volatile("s_waitcnt vmcnt(0)" ::: "memory");                                \
    }                                                                                 \
    asm volatile("s_waitcnt lgkmcnt(0)" ::: "memory");                                \
    __builtin_amdgcn_sched_barrier(0);                                                \
    __builtin_amdgcn_s_barrier();                                                     \
  } while (0)

    for (int T = 0; T < nt; T += 2) {
        TILEDP(0, T);
        TILEDP(1, T + 1);
    }
#undef TILEDP
#undef SAD
#undef SBD

    // ---- epilogue ----
    if constexpr (OPROJ) {
        float* Cp = (float*)C0;
#pragma unroll
        for (int i = 0; i < 4; ++i) {
            int gm = m0 + wm * 64 + i * 16 + hi * 4;
#pragma unroll
            for (int jj = 0; jj < 4; ++jj) {
                int gn = n0 + wn * 64 + jj * 16 + lo;
#pragma unroll
                for (int r = 0; r < 4; ++r)
                    Cp[(size_t)(gm + r) * N + gn] = acc[i][jj][r];
            }
        }
    } else {
        if (n0 >= 5120) {
            // V region: write transposed straight into Vt (B,HKV,D,S)
#pragma unroll
            for (int i = 0; i < 4; ++i) {
                int gm = m0 + wm * 64 + i * 16 + hi * 4;
                int bb = gm >> 11, s = gm & (SS - 1);
#pragma unroll
                for (int jj = 0; jj < 4; ++jj) {
                    int gn = (n0 - 5120) + wn * 64 + jj * 16 + lo;
                    int hkv = gn >> 7, d = gn & 127;
                    us4 o;
#pragma unroll
                    for (int r = 0; r < 4; ++r) o[r] = f2bf(acc[i][jj][r]);
                    *(us4*)(Vt_ + (((size_t)(bb * NKV + hkv) * DD + d) * SS + s)) = o;
                }
            }
        } else {
            u16* Cb;
            int cstride, cn0;
            if (n0 < 4096) { Cb = (u16*)C0; cstride = NH * DD;  cn0 = n0; }
            else           { Cb = Kb_;      cstride = NKV * DD; cn0 = n0 - 4096; }
#pragma unroll
            for (int i = 0; i < 4; ++i) {
                int gm = m0 + wm * 64 + i * 16 + hi * 4;
#pragma unroll
                for (int jj = 0; jj < 4; ++jj) {
                    int gn = cn0 + wn * 64 + jj * 16 + lo;
#pragma unroll
                    for (int r = 0; r < 4; ++r)
                        Cb[(size_t)(gm + r) * cstride + gn] = f2bf(acc[i][jj][r]);
                }
            }
        }
    }
}

// ---------------------------------------------------------------------------
// RoPE (rotate-half) on bf16 (B,S,nheads,D); scale folded into Q.
// ---------------------------------------------------------------------------
__global__ __launch_bounds__(256) void rope_k(u16* buf,
                                              const float* __restrict__ cosT,
                                              const float* __restrict__ sinT,
                                              int nheads, float scale)
{
    int idx = blockIdx.x * 256 + threadIdx.x;
    int total = BB * SS * nheads * 64;
    if (idx >= total) return;
    int d = idx & 63;
    int rem = idx >> 6;
    int hh = rem % nheads;
    int s = (rem / nheads) & (SS - 1);
    int bb = rem / (nheads * SS);
    size_t base = ((size_t)(bb * SS + s) * nheads + hh) * DD;
    float x0 = bf2f(buf[base + d]), x1 = bf2f(buf[base + d + 64]);
    float c = cosT[s * DD + d], sn = sinT[s * DD + d];
    buf[base + d]      = f2bf((x0 * c - x1 * sn) * scale);
    buf[base + d + 64] = f2bf((x0 * sn + x1 * c) * scale);
}

// ---------------------------------------------------------------------------
// P-exchange: 8 f32 P-values -> bf16 A-fragment (cvt_pk + shfl_xor(32)).
// ---------------------------------------------------------------------------
__device__ __forceinline__ short8 make_pa(float p0, float p1, float p2, float p3,
                                          float p4, float p5, float p6, float p7,
                                          int hi1)
{
    unsigned w0, w1, w2, w3;
    asm("v_cvt_pk_bf16_f32 %0, %1, %2" : "=v"(w0) : "v"(p0), "v"(p1));
    asm("v_cvt_pk_bf16_f32 %0, %1, %2" : "=v"(w1) : "v"(p2), "v"(p3));
    asm("v_cvt_pk_bf16_f32 %0, %1, %2" : "=v"(w2) : "v"(p4), "v"(p5));
    asm("v_cvt_pk_bf16_f32 %0, %1, %2" : "=v"(w3) : "v"(p6), "v"(p7));
    unsigned xw0 = (unsigned)__shfl_xor((int)w0, 32);
    unsigned xw1 = (unsigned)__shfl_xor((int)w1, 32);
    unsigned xw2 = (unsigned)__shfl_xor((int)w2, 32);
    unsigned xw3 = (unsigned)__shfl_xor((int)w3, 32);
    union { unsigned u[4]; short8 s; } cv;
    cv.u[0] = hi1 ? xw2 : w0;
    cv.u[1] = hi1 ? xw3 : w1;
    cv.u[2] = hi1 ? w2 : xw0;
    cv.u[3] = hi1 ? w3 : xw1;
    return cv.s;
}

// ---------------------------------------------------------------------------
// Flash attention v9 (verified): QBLK=256, 8 waves, 512 threads, all 512
// blocks resident, pair-balanced qt, XCD-chunk L2 locality.
// ---------------------------------------------------------------------------
__global__ __launch_bounds__(512, 2) void attn9_k(const u16* __restrict__ Qb,
                                                  const u16* __restrict__ Kb,
                                                  const u16* __restrict__ Vt,
                                                  u16* __restrict__ AO)
{
    const int wgid = blockIdx.x;
    const int k = wgid & 7;
    const int j = wgid >> 3;
    const int u = j & 31, v = j >> 5;
    const int qtb = u >> 3;
    const int qt = v ? 7 - qtb : qtb;
    const int h  = (k & 3) * 8 + (u & 7);
    const int b  = k >> 2;
    const int hkv = h >> 2;
    const int tid = threadIdx.x;
    const int w = tid >> 6, lane = tid & 63;
    const int l31 = lane & 31, hi1 = lane >> 5;
    const int qr0 = qt * 256 + w * 32;

    __shared__ u16 Kl[2][64 * 128];
    __shared__ u16 Vl[2][128 * 64];

    short8 qf[8];
    {
        const u16* qrow = Qb + ((size_t)(b * SS + qr0 + l31) * NH + h) * DD + hi1 * 8;
#pragma unroll
        for (int ks = 0; ks < 8; ++ks) qf[ks] = *(const short8*)(qrow + ks * 16);
    }

    const u16* kbase = Kb + ((size_t)b * SS * NKV + hkv) * DD;
    const u16* vbase = Vt + (size_t)(b * NKV + hkv) * DD * SS;

    f32x16 oacc[4] = {};
    float mreg = -INFINITY, lreg = 0.f;

    const int nkt = 4 * qt + 4;
    const int rk = lane >> 4, sk = lane & 15;
    const int rv = lane >> 3, sv = lane & 7;

#pragma unroll
    for (int i = 0; i < 2; ++i) {
        const int c = w * 2 + i;
        const int krow = c * 4 + rk;
        GLOAD16(kbase + (size_t)krow * (NKV * DD) + ((sk ^ (krow & 15)) * 8), &Kl[0][c * 512]);
        const int vrow = c * 8 + rv;
        GLOAD16(vbase + (size_t)vrow * SS + ((sv ^ (vrow & 7)) * 8), &Vl[0][c * 512]);
    }
    __syncthreads();

    int buf = 0;
    for (int kt = 0; kt < nkt; ++kt) {
        const int kv0 = kt * 64;
        if (kt + 1 < nkt) {
            const int kv1 = kv0 + 64;
#pragma unroll
            for (int i = 0; i < 2; ++i) {
                const int c = w * 2 + i;
                const int krow = c * 4 + rk;
                GLOAD16(kbase + (size_t)(kv1 + krow) * (NKV * DD) + ((sk ^ (krow & 15)) * 8),
                        &Kl[buf ^ 1][c * 512]);
                const int vrow = c * 8 + rv;
                GLOAD16(vbase + (size_t)vrow * SS + kv1 + ((sv ^ (vrow & 7)) * 8),
                        &Vl[buf ^ 1][c * 512]);
            }
        }

        if (kv0 <= qr0 + 31) {
            const u16* Kc = Kl[buf];
            const u16* Vc = Vl[buf];

            f32x16 s0 = {}, s1 = {};
            __builtin_amdgcn_s_setprio(1);
#pragma unroll
            for (int ks = 0; ks < 8; ++ks) {
                const int slot = (((2 * ks + hi1) ^ sk) * 8);
                short8 kf0 = *(const short8*)&Kc[l31 * 128 + slot];
                s0 = MFMA32(kf0, qf[ks], s0);
                short8 kf1 = *(const short8*)&Kc[(32 + l31) * 128 + slot];
                s1 = MFMA32(kf1, qf[ks], s1);
            }
            __builtin_amdgcn_s_setprio(0);

            const int qab = qr0 + l31;
            if (kv0 + 63 > qr0) {
#pragma unroll
                for (int r = 0; r < 16; ++r) {
                    const int off = (r & 3) + 8 * (r >> 2) + 4 * hi1;
                    if (kv0 + off > qab)      s0[r] = -INFINITY;
                    if (kv0 + 32 + off > qab) s1[r] = -INFINITY;
                }
            }
            float m0 = fmaxf(s0[0], s1[0]), m1 = fmaxf(s0[1], s1[1]);
            float m2 = fmaxf(s0[2], s1[2]), m3 = fmaxf(s0[3], s1[3]);
#pragma unroll
            for (int r = 4; r < 16; r += 4) {
                m0 = fmaxf(m0, fmaxf(s0[r],     s1[r]));
                m1 = fmaxf(m1, fmaxf(s0[r + 1], s1[r + 1]));
                m2 = fmaxf(m2, fmaxf(s0[r + 2], s1[r + 2]));
                m3 = fmaxf(m3, fmaxf(s0[r + 3], s1[r + 3]));
            }
            float mx = fmaxf(fmaxf(m0, m1), fmaxf(m2, m3));
            mx = fmaxf(mx, __shfl_xor(mx, 32));

            if (__any(mx > mreg + 8.0f)) {
                const float nm = fmaxf(mreg, mx);
                const float al = exp2f(mreg - nm);
                mreg = nm;
                lreg *= al;
#pragma unroll
                for (int r = 0; r < 16; ++r) {
                    const float ar = __shfl(al, (r & 3) + 8 * (r >> 2) + 4 * hi1);
#pragma unroll
                    for (int db = 0; db < 4; ++db) oacc[db][r] *= ar;
                }
            }

#pragma unroll
            for (int r = 0; r < 16; ++r) {
                s0[r] = exp2f(s0[r] - mreg);
                s1[r] = exp2f(s1[r] - mreg);
            }
            float sa = 0.f, sb = 0.f, sc_ = 0.f, sd = 0.f;
#pragma unroll
            for (int r = 0; r < 16; r += 4) {
                sa  += s0[r]     + s1[r];
                sb  += s0[r + 1] + s1[r + 1];
                sc_ += s0[r + 2] + s1[r + 2];
                sd  += s0[r + 3] + s1[r + 3];
            }
            lreg += (sa + sb) + (sc_ + sd);

            short8 pa0 = make_pa(s0[0], s0[1], s0[2],  s0[3],  s0[4],  s0[5],  s0[6],  s0[7],  hi1);
            short8 pa1 = make_pa(s0[8], s0[9], s0[10], s0[11], s0[12], s0[13], s0[14], s0[15], hi1);
            short8 pa2 = make_pa(s1[0], s1[1], s1[2],  s1[3],  s1[4],  s1[5],  s1[6],  s1[7],  hi1);
            short8 pa3 = make_pa(s1[8], s1[9], s1[10], s1[11], s1[12], s1[13], s1[14], s1[15], hi1);

            __builtin_amdgcn_s_setprio(1);
#pragma unroll
            for (int db = 0; db < 4; ++db) {
                const int vr = (db * 32 + l31) * 64;
                short8 vf0 = *(const short8*)&Vc[vr + (((0 + hi1) ^ sv) * 8)];
                oacc[db] = MFMA32(pa0, vf0, oacc[db]);
                short8 vf1 = *(const short8*)&Vc[vr + (((2 + hi1) ^ sv) * 8)];
                oacc[db] = MFMA32(pa1, vf1, oacc[db]);
                short8 vf2 = *(const short8*)&Vc[vr + (((4 + hi1) ^ sv) * 8)];
                oacc[db] = MFMA32(pa2, vf2, oacc[db]);
                short8 vf3 = *(const short8*)&Vc[vr + (((6 + hi1) ^ sv) * 8)];
                oacc[db] = MFMA32(pa3, vf3, oacc[db]);
            }
            __builtin_amdgcn_s_setprio(0);
        }
        __syncthreads();
        buf ^= 1;
    }

    const float lf = lreg + __shfl_xor(lreg, 32);
#pragma unroll
    for (int r = 0; r < 16; ++r) {
        const int qrw = (r & 3) + 8 * (r >> 2) + 4 * hi1;
        const float linv = 1.0f / __shfl(lf, qrw);
        u16* orow = AO + ((size_t)(b * SS + qr0 + qrw) * NH + h) * DD + l31;
#pragma unroll
        for (int db = 0; db < 4; ++db)
            orow[db * 32] = f2bf(oacc[db][r] * linv);
    }
}

// ===========================================================================
// FALLBACK (round-1 proven path, used only if ws_size is too small)
// ===========================================================================
template<bool A_BF16, bool C_F32>
__global__ __launch_bounds__(256) void gemm_k(const void* __restrict__ Ap,
                                              const float* __restrict__ Bp,
                                              void* __restrict__ Cp,
                                              int M, int N, int K)
{
    __shared__ u16 Asm[128 * 40];
    __shared__ u16 Bsm[128 * 40];
    const int tid  = threadIdx.x;
    const int lane = tid & 63, wid = tid >> 6;
    const int lo = lane & 15, hi = lane >> 4;
    const int wm = wid >> 1, wn = wid & 1;
    const int m0 = blockIdx.y * 128, n0 = blockIdx.x * 128;
    f32x4 acc[4][4] = {};
    const int nkt = K >> 5;
    for (int kt = 0; kt < nkt; ++kt) {
        const int k0 = kt << 5;
        __syncthreads();
        if constexpr (A_BF16) {
            const u16* A = (const u16*)Ap;
#pragma unroll
            for (int it = 0; it < 4; ++it) {
                int f = it * 256 + tid;
                int row = f >> 3, kg = (f & 7) * 4;
                us4 v = *(const us4*)(A + (size_t)(m0 + row) * K + k0 + kg);
#pragma unroll
                for (int j = 0; j < 4; ++j) Asm[row * 40 + kg + j] = v[j];
            }
        } else {
            const float* A = (const float*)Ap;
#pragma unroll
            for (int it = 0; it < 4; ++it) {
                int f = it * 256 + tid;
                int row = f >> 3, kg = (f & 7) * 4;
                f32x4 v = *(const f32x4*)(A + (size_t)(m0 + row) * K + k0 + kg);
#pragma unroll
                for (int j = 0; j < 4; ++j) Asm[row * 40 + kg + j] = f2bf(v[j]);
            }
        }
#pragma unroll
        for (int it = 0; it < 4; ++it) {
            int f = it * 256 + tid;
            int kr = f >> 5, cg = (f & 31) * 4;
            f32x4 v = *(const f32x4*)(Bp + (size_t)(k0 + kr) * N + n0 + cg);
#pragma unroll
            for (int j = 0; j < 4; ++j) Bsm[(cg + j) * 40 + kr] = f2bf(v[j]);
        }
        __syncthreads();
        short8 af[4], bfr[4];
#pragma unroll
        for (int i = 0; i < 4; ++i)
            af[i] = *(const short8*)&Asm[(wm * 64 + i * 16 + lo) * 40 + hi * 8];
#pragma unroll
        for (int j = 0; j < 4; ++j)
            bfr[j] = *(const short8*)&Bsm[(wn * 64 + j * 16 + lo) * 40 + hi * 8];
#pragma unroll
        for (int i = 0; i < 4; ++i)
#pragma unroll
            for (int j = 0; j < 4; ++j)
                acc[i][j] = MFMA16(af[i], bfr[j], acc[i][j]);
    }
#pragma unroll
    for (int i = 0; i < 4; ++i) {
        int gm = m0 + wm * 64 + i * 16 + hi * 4;
#pragma unroll
        for (int j = 0; j < 4; ++j) {
            int gn = n0 + wn * 64 + j * 16 + lo;
#pragma unroll
            for (int r = 0; r < 4; ++r) {
                if constexpr (C_F32)
                    ((float*)Cp)[(size_t)(gm + r) * N + gn] = acc[i][j][r];
                else
                    ((u16*)Cp)[(size_t)(gm + r) * N + gn] = f2bf(acc[i][j][r]);
            }
        }
    }
}

__global__ __launch_bounds__(64) void attn_k(const u16* __restrict__ Qb,
                                             const u16* __restrict__ Kb,
                                             const u16* __restrict__ Vb,
                                             u16* __restrict__ AO)
{
    const int blk = blockIdx.x;
    const int qt = blk & (SS / 16 - 1);
    const int h  = (blk >> 7) & (NH - 1);
    const int b  = blk >> 12;
    const int hkv = h >> 2;
    const int lane = threadIdx.x;
    const int lo = lane & 15, hi = lane >> 4;
    const int qbase = qt * 16;
    __shared__ float sc[16][32];
    __shared__ u16 vt[128 * 40];
    short8 qf[4];
    const u16* qrow = Qb + ((size_t)(b * SS + qbase + lo) * NH + h) * DD;
#pragma unroll
    for (int c = 0; c < 4; ++c) qf[c] = *(const short8*)(qrow + c * 32 + hi * 8);
    f32x4 oacc[8] = {};
    float m[4] = {-INFINITY, -INFINITY, -INFINITY, -INFINITY};
    float l[4] = {0.f, 0.f, 0.f, 0.f};
    const int nkt = (qbase + 16 + 31) >> 5;
    for (int kt = 0; kt < nkt; ++kt) {
        const int kv0 = kt << 5;
        f32x4 s0 = {}, s1 = {};
        const u16* kb0 = Kb + ((size_t)(b * SS + kv0) * NKV + hkv) * DD;
#pragma unroll
        for (int c = 0; c < 4; ++c) {
            short8 k0f = *(const short8*)(kb0 + (size_t)lo * (NKV * DD) + c * 32 + hi * 8);
            short8 k1f = *(const short8*)(kb0 + (size_t)(lo + 16) * (NKV * DD) + c * 32 + hi * 8);
            s0 = MFMA16(qf[c], k0f, s0);
            s1 = MFMA16(qf[c], k1f, s1);
        }
#pragma unroll
        for (int i = 0; i < 8; ++i) {
            int g = i * 64 + lane;
            int row = g >> 4, dg = (g & 15) * 8;
            short8 vv = *(const short8*)(Vb + ((size_t)(b * SS + kv0 + row) * NKV + hkv) * DD + dg);
#pragma unroll
            for (int j = 0; j < 8; ++j) vt[(dg + j) * 40 + row] = (u16)vv[j];
        }
        float alpha[4];
#pragma unroll
        for (int r = 0; r < 4; ++r) {
            int qrowi = qbase + hi * 4 + r;
            float v0 = s0[r]; if (kv0 + lo > qrowi)      v0 = -INFINITY;
            float v1 = s1[r]; if (kv0 + 16 + lo > qrowi) v1 = -INFINITY;
            float mx = fmaxf(v0, v1);
#pragma unroll
            for (int off = 1; off < 16; off <<= 1) mx = fmaxf(mx, __shfl_xor(mx, off, 64));
            float nm = fmaxf(m[r], mx);
            float a = __expf(m[r] - nm);
            v0 = __expf(v0 - nm);
            v1 = __expf(v1 - nm);
            float ps = v0 + v1;
#pragma unroll
            for (int off = 1; off < 16; off <<= 1) ps += __shfl_xor(ps, off, 64);
            l[r] = l[r] * a + ps;
            m[r] = nm;
            alpha[r] = a;
            sc[hi * 4 + r][lo] = v0;
            sc[hi * 4 + r][16 + lo] = v1;
        }
#pragma unroll
        for (int n = 0; n < 8; ++n)
#pragma unroll
            for (int r = 0; r < 4; ++r) oacc[n][r] *= alpha[r];
        __syncthreads();
        f32x4 p0 = *(const f32x4*)&sc[lo][hi * 8];
        f32x4 p1 = *(const f32x4*)&sc[lo][hi * 8 + 4];
        short8 pf;
#pragma unroll
        for (int j = 0; j < 4; ++j) {
            pf[j]     = (short)f2bf(p0[j]);
            pf[4 + j] = (short)f2bf(p1[j]);
        }
#pragma unroll
        for (int n = 0; n < 8; ++n) {
            short8 vf = *(const short8*)&vt[(n * 16 + lo) * 40 + hi * 8];
            oacc[n] = MFMA16(pf, vf, oacc[n]);
        }
        __syncthreads();
    }
#pragma unroll
    for (int n = 0; n < 8; ++n) {
#pragma unroll
        for (int r = 0; r < 4; ++r) {
            size_t idx = ((size_t)(b * SS + qbase + hi * 4 + r) * NH + h) * DD + n * 16 + lo;
            AO[idx] = f2bf(oacc[n][r] / l[r]);
        }
    }
}

// ---------------------------------------------------------------------------
extern "C" void kernel_launch(void* const* d_in, const int* in_sizes, int n_in,
                              void* d_out, int out_size, void* d_ws, size_t ws_size,
                              hipStream_t stream) {
    const float* hs   = (const float*)d_in[0];
    const float* sinT = (const float*)d_in[1];
    const float* cosT = (const float*)d_in[2];
    const float* Wq   = (const float*)d_in[3];
    const float* Wk   = (const float*)d_in[4];
    const float* Wv   = (const float*)d_in[5];
    const float* Wo   = (const float*)d_in[6];
    float* out = (float*)d_out;
    const int M = BB * SS;
    u16* ws = (u16*)d_ws;

    const size_t NEED = 109051904;  // bytes (54,525,952 u16)
    if (ws_size >= NEED) {
        u16* Qb   = ws;                 // [0, 16777216)
        u16* Kb   = ws + 16777216;      // [16777216, 20971520)
        u16* Vt   = ws + 25165824;      // [25165824, 29360128)
        u16* Wcat = ws + 29360128;      // [29360128, 41943040)  6144x2048
        u16* hsb  = ws + 41943040;      // [41943040, 50331648)
        u16* Wot  = Wcat;               // reuse after QKV gemm
        u16* AO   = ws + 37748736;      // [37748736, 54525952)  after Wot transpose

        cvt_k<<<4096, 256, 0, stream>>>(hs, hsb, (M * HID) / 8);
        // Wcat rows: [0,4096)=Wq^T, [4096,5120)=Wk^T, [5120,6144)=Wv^T
        tw_k<<<dim3(4096 / 32, 2048 / 32), 256, 0, stream>>>(Wq, Wcat, HID, NH * DD);
        tw_k<<<dim3(1024 / 32, 2048 / 32), 256, 0, stream>>>(Wk, Wcat + (size_t)4096 * 2048, HID, NKV * DD);
        tw_k<<<dim3(1024 / 32, 2048 / 32), 256, 0, stream>>>(Wv, Wcat + (size_t)5120 * 2048, HID, NKV * DD);

        // fused QKV projection (256x128 deep pipeline, 768 blocks = 3 rounds)
        gemmdp_k<false><<<768, 512, 0, stream>>>(hsb, Wcat, Qb, Kb, Vt, HID, 0);

        // Q scale = (1/sqrt(128)) * log2(e)  [softmax in exp2 domain]
        rope_k<<<(BB * SS * NH * 64 + 255) / 256, 256, 0, stream>>>(Qb, cosT, sinT, NH, 0.12751744f);
        rope_k<<<(BB * SS * NKV * 64 + 255) / 256, 256, 0, stream>>>(Kb, cosT, sinT, NKV, 1.0f);
        tw_k<<<dim3(2048 / 32, 4096 / 32), 256, 0, stream>>>(Wo, Wot, NH * DD, HID);

        attn9_k<<<SS / 256 * NH * BB, 512, 0, stream>>>(Qb, Kb, Vt, AO);

        // output projection (256x128 deep pipeline, 256 blocks = 1 round)
        gemmdp_k<true><<<256, 512, 0, stream>>>(AO, Wot, out, nullptr, nullptr, NH * DD, HID);
    } else {
        u16* Qb   = ws;
        u16* Kbuf = Qb   + (size_t)BB * SS * NH * DD;
        u16* Vbuf = Kbuf + (size_t)BB * SS * NKV * DD;
        u16* AO   = Vbuf + (size_t)BB * SS * NKV * DD;

        gemm_k<false, false><<<dim3((NH * DD) / 128, M / 128), 256, 0, stream>>>(hs, Wq, Qb, M, NH * DD, HID);
        gemm_k<false, false><<<dim3((NKV * DD) / 128, M / 128), 256, 0, stream>>>(hs, Wk, Kbuf, M, NKV * DD, HID);
        gemm_k<false, false><<<dim3((NKV * DD) / 128, M / 128), 256, 0, stream>>>(hs, Wv, Vbuf, M, NKV * DD, HID);
        rope_k<<<(BB * SS * NH * 64 + 255) / 256, 256, 0, stream>>>(Qb, cosT, sinT, NH, 0.08838834764831845f);
        rope_k<<<(BB * SS * NKV * 64 + 255) / 256, 256, 0, stream>>>(Kbuf, cosT, sinT, NKV, 1.0f);
        attn_k<<<BB * NH * (SS / 16), 64, 0, stream>>>(Qb, Kbuf, Vbuf, AO);
        gemm_k<true, true><<<dim3(HID / 128, M / 128), 256, 0, stream>>>(AO, Wo, out, M, HID, NH * DD);
    }
}

// Round 13
// 360.018 us; speedup vs baseline: 1.0153x; 1.0153x over previous
//
#include <hip/hip_runtime.h>
#include <hip/hip_bf16.h>
#include <math.h>

#define BB 2
#define SS 2048
#define HID 2048
#define NH 32
#define NKV 8
#define DD 128

typedef unsigned short u16;
typedef __attribute__((ext_vector_type(8))) short short8;
typedef __attribute__((ext_vector_type(4))) float f32x4;
typedef __attribute__((ext_vector_type(16))) float f32x16;
typedef __attribute__((ext_vector_type(4))) unsigned short us4;

__device__ __forceinline__ u16 f2bf(float f) {
    unsigned int u = __float_as_uint(f);
    u += 0x7fff + ((u >> 16) & 1);
    return (u16)(u >> 16);
}
__device__ __forceinline__ float bf2f(u16 h) {
    return __uint_as_float(((unsigned int)h) << 16);
}

#define GLOAD16(gp, lp) __builtin_amdgcn_global_load_lds(                      \
    (const __attribute__((address_space(1))) void*)(gp),                       \
    (__attribute__((address_space(3))) void*)(lp), 16, 0, 0)

#define MFMA32(a, b, c) __builtin_amdgcn_mfma_f32_32x32x16_bf16(a, b, c, 0, 0, 0)
#define MFMA16(a, b, c) __builtin_amdgcn_mfma_f32_16x16x32_bf16(a, b, c, 0, 0, 0)

// ---------------------------------------------------------------------------
// cvt: fp32 -> bf16 elementwise (8 elems/thread)
// ---------------------------------------------------------------------------
__global__ __launch_bounds__(256) void cvt_k(const float* __restrict__ in,
                                             u16* __restrict__ out, int n8)
{
    int i = blockIdx.x * 256 + threadIdx.x;
    if (i >= n8) return;
    f32x4 a = ((const f32x4*)in)[i * 2];
    f32x4 b = ((const f32x4*)in)[i * 2 + 1];
    short8 o;
#pragma unroll
    for (int j = 0; j < 4; ++j) { o[j] = (short)f2bf(a[j]); o[4 + j] = (short)f2bf(b[j]); }
    ((short8*)out)[i] = o;
}

// ---------------------------------------------------------------------------
// transpose + convert: fp32 in[R][C] -> bf16 out[C][R]. 32x32 tiles.
// ---------------------------------------------------------------------------
__global__ __launch_bounds__(256) void tw_k(const float* __restrict__ in,
                                            u16* __restrict__ out, int R, int C)
{
    __shared__ float t[32][33];
    const int tc = blockIdx.x * 32, tr = blockIdx.y * 32;
    const int r = threadIdx.x >> 3, c4 = (threadIdx.x & 7) * 4;
    f32x4 v = *(const f32x4*)(in + (size_t)(tr + r) * C + tc + c4);
#pragma unroll
    for (int j = 0; j < 4; ++j) t[r][c4 + j] = v[j];
    __syncthreads();
    us4 o;
#pragma unroll
    for (int j = 0; j < 4; ++j) o[j] = f2bf(t[c4 + j][r]);
    *(us4*)(out + (size_t)(tc + r) * R + tr + c4) = o;
}

// ---------------------------------------------------------------------------
// V transpose (fallback-path only): Vb (B,S,HKV,D) -> Vt (B,HKV,D,S).
// ---------------------------------------------------------------------------
__global__ __launch_bounds__(256) void vtr_k(const u16* __restrict__ Vb,
                                             u16* __restrict__ Vt)
{
    __shared__ u16 t[64][72];
    const int s0 = blockIdx.x * 64, d0 = blockIdx.y * 64;
    const int b = blockIdx.z >> 3, hkv = blockIdx.z & 7;
    const int tid = threadIdx.x;
    const int rr = tid >> 3, cc = (tid & 7) * 8;
#pragma unroll
    for (int it = 0; it < 2; ++it) {
        int row = rr + it * 32;
        short8 v = *(const short8*)(Vb + ((size_t)(b * SS + s0 + row) * NKV + hkv) * DD + d0 + cc);
#pragma unroll
        for (int j = 0; j < 8; ++j) t[row][cc + j] = (u16)v[j];
    }
    __syncthreads();
#pragma unroll
    for (int it = 0; it < 2; ++it) {
        int dr = rr + it * 32;
        short8 o;
#pragma unroll
        for (int j = 0; j < 8; ++j) o[j] = (short)t[cc + j][dr];
        *(short8*)(Vt + ((size_t)(b * NKV + hkv) * DD + d0 + dr) * SS + s0 + cc) = o;
    }
}

// ---------------------------------------------------------------------------
// QKV projection GEMM v3: 256x256 tile, BK=64, 8 waves, deep pipeline with
// the m201 DOUBLE-BARRIER phase for p0/p1:
//   {ds_reads -> sched_barrier -> s_barrier -> lgkmcnt(0) -> sched_barrier ->
//    setprio(1) 16xMFMA setprio(0) -> s_barrier}
// so ds_read latency drains during the barrier wait and the MFMA burst is
// pure. p2/p3 are register-only MFMA + staging (T+2) + counted vmcnt(8).
// Slot(h of tile T) = (2T+h)&3; reads of a slot complete (lgkmcnt before a
// barrier) >=1 barrier before its restage is issued -> race-free.
// Epilogue routes cols: [0,4096)->Qb, [4096,5120)->Kb, [5120,6144)->Vt^T.
// ---------------------------------------------------------------------------
__global__ __launch_bounds__(512, 2) void gemm8qkv_k(const u16* __restrict__ A,
                                                     const u16* __restrict__ Bt,
                                                     u16* __restrict__ Qb_,
                                                     u16* __restrict__ Kb_,
                                                     u16* __restrict__ Vt_)
{
    const int K = HID;                         // 2048, nt = 32
    const int k8 = blockIdx.x & 7;
    const int j  = (int)blockIdx.x >> 3;       // 0..47
    const int bx = j >> 1, by = k8 * 2 + (j & 1);
    const int m0 = by * 256, n0 = bx * 256;

    __shared__ u16 Asl[4][128 * 64];
    __shared__ u16 Bsl[4][128 * 64];

    const int tid = threadIdx.x;
    const int w = tid >> 6, lane = tid & 63;
    const int wm = w >> 2, wn = w & 3;
    const int lo = lane & 15, hi = lane >> 4;
    const int brow0 = (wn & 1) * 64;

    const int srow8 = lane >> 3;
    const int skk = ((lane & 7) ^ srow8) * 8;
    const u16* As = A + (size_t)(m0 + w * 16 + srow8) * K + skk;
    const u16* Bs = Bt + (size_t)(n0 + w * 16 + srow8) * K + skk;

#define SA8(slot, half, kof) do {                                                        \
    GLOAD16(As + (size_t)((half) * 128) * K + (kof), &Asl[slot][(w * 16) * 64]);         \
    GLOAD16(As + (size_t)((half) * 128 + 8) * K + (kof), &Asl[slot][(w * 16 + 8) * 64]); \
  } while (0)
#define SB8(slot, half, kof) do {                                                        \
    GLOAD16(Bs + (size_t)((half) * 128) * K + (kof), &Bsl[slot][(w * 16) * 64]);         \
    GLOAD16(Bs + (size_t)((half) * 128 + 8) * K + (kof), &Bsl[slot][(w * 16 + 8) * 64]); \
  } while (0)

    f32x4 acc[8][4] = {};
    const int nt = K >> 6;                    // 32

    // ---- prologue: stage tiles 0 (slots 0,1) and 1 (slots 2,3) ----
    SA8(0, 0, 0);  SA8(1, 1, 0);  SB8(0, 0, 0);  SB8(1, 1, 0);
    SA8(2, 0, 64); SA8(3, 1, 64); SB8(2, 0, 64); SB8(3, 1, 64);
    asm volatile("s_waitcnt vmcnt(8)" ::: "memory");   // tile0 landed
    __builtin_amdgcn_s_barrier();

#define TILE8(P, T) do {                                                                 \
    const u16* Apan = Asl[(P) * 2 + wm];                                                 \
    const u16* Bpan = Bsl[(P) * 2 + (wn >> 1)];                                          \
    short8 afr[2][8]; short8 bfr[2][4];                                                  \
    /* ---- p0: issue reads A[0..3]/B[0..1]; DBL-BARRIER; MFMA i0-3 x j0-1 ---- */       \
    _Pragma("unroll") for (int c = 0; c < 2; ++c) {                                      \
      _Pragma("unroll") for (int i = 0; i < 4; ++i)                                      \
        afr[c][i] = *(const short8*)&Apan[(i * 16 + lo) * 64 + (((c * 4 + hi) ^ (lo & 7)) * 8)]; \
      _Pragma("unroll") for (int jj = 0; jj < 2; ++jj)                                   \
        bfr[c][jj] = *(const short8*)&Bpan[(brow0 + jj * 16 + lo) * 64 + (((c * 4 + hi) ^ (lo & 7)) * 8)]; \
    }                                                                                    \
    __builtin_amdgcn_sched_barrier(0);                                                   \
    __builtin_amdgcn_s_barrier();                                                        \
    asm volatile("s_waitcnt lgkmcnt(0)" ::: "memory");                                   \
    __builtin_amdgcn_sched_barrier(0);                                                   \
    __builtin_amdgcn_s_setprio(1);                                                       \
    _Pragma("unroll") for (int i = 0; i < 4; ++i)                                        \
      _Pragma("unroll") for (int jj = 0; jj < 2; ++jj) {                                 \
        acc[i][jj] = MFMA16(afr[0][i], bfr[0][jj], acc[i][jj]);                          \
        acc[i][jj] = MFMA16(afr[1][i], bfr[1][jj], acc[i][jj]);                          \
      }                                                                                  \
    __builtin_amdgcn_s_setprio(0);                                                       \
    __builtin_amdgcn_s_barrier();                                                        \
    /* ---- p1: issue reads A[4..7]/B[2..3]; DBL-BARRIER; MFMA i0-3 x j2-3 ---- */       \
    _Pragma("unroll") for (int c = 0; c < 2; ++c) {                                      \
      _Pragma("unroll") for (int i = 4; i < 8; ++i)                                      \
        afr[c][i] = *(const short8*)&Apan[(i * 16 + lo) * 64 + (((c * 4 + hi) ^ (lo & 7)) * 8)]; \
      _Pragma("unroll") for (int jj = 2; jj < 4; ++jj)                                   \
        bfr[c][jj] = *(const short8*)&Bpan[(brow0 + jj * 16 + lo) * 64 + (((c * 4 + hi) ^ (lo & 7)) * 8)]; \
    }                                                                                    \
    __builtin_amdgcn_sched_barrier(0);                                                   \
    __builtin_amdgcn_s_barrier();                                                        \
    asm volatile("s_waitcnt lgkmcnt(0)" ::: "memory");                                   \
    __builtin_amdgcn_sched_barrier(0);                                                   \
    __builtin_amdgcn_s_setprio(1);                                                       \
    _Pragma("unroll") for (int i = 0; i < 4; ++i)                                        \
      _Pragma("unroll") for (int jj = 2; jj < 4; ++jj) {                                 \
        acc[i][jj] = MFMA16(afr[0][i], bfr[0][jj], acc[i][jj]);                          \
        acc[i][jj] = MFMA16(afr[1][i], bfr[1][jj], acc[i][jj]);                          \
      }                                                                                  \
    __builtin_amdgcn_s_setprio(0);                                                       \
    __builtin_amdgcn_s_barrier();                                                        \
    /* ---- p2: MFMA i4-7 x j0-1; issue A-stage of T+2 ---- */                           \
    __builtin_amdgcn_s_setprio(1);                                                       \
    _Pragma("unroll") for (int i = 4; i < 8; ++i)                                        \
      _Pragma("unroll") for (int jj = 0; jj < 2; ++jj) {                                 \
        acc[i][jj] = MFMA16(afr[0][i], bfr[0][jj], acc[i][jj]);                          \
        acc[i][jj] = MFMA16(afr[1][i], bfr[1][jj], acc[i][jj]);                          \
      }                                                                                  \
    __builtin_amdgcn_s_setprio(0);                                                       \
    if ((T) + 2 < nt) {                                                                  \
      SA8((P) * 2 + 0, 0, ((T) + 2) * 64); SA8((P) * 2 + 1, 1, ((T) + 2) * 64);          \
    }                                                                                    \
    __builtin_amdgcn_sched_barrier(0);                                                   \
    __builtin_amdgcn_s_barrier();                                                        \
    /* ---- p3: MFMA i4-7 x j2-3; issue B-stage of T+2; counted vmcnt ---- */            \
    __builtin_amdgcn_s_setprio(1);                                                       \
    _Pragma("unroll") for (int i = 4; i < 8; ++i)                                        \
      _Pragma("unroll") for (int jj = 2; jj < 4; ++jj) {                                 \
        acc[i][jj] = MFMA16(afr[0][i], bfr[0][jj], acc[i][jj]);                          \
        acc[i][jj] = MFMA16(afr[1][i], bfr[1][jj], acc[i][jj]);                          \
      }                                                                                  \
    __builtin_amdgcn_s_setprio(0);                                                       \
    if ((T) + 2 < nt) {                                                                  \
      SB8((P) * 2 + 0, 0, ((T) + 2) * 64); SB8((P) * 2 + 1, 1, ((T) + 2) * 64);          \
      asm volatile("s_waitcnt vmcnt(8)" ::: "memory");                                   \
    } else {                                                                             \
      asm volatile("s_waitcnt vmcnt(0)" ::: "memory");                                   \
    }                                                                                    \
    asm volatile("s_waitcnt lgkmcnt(0)" ::: "memory");                                   \
    __builtin_amdgcn_sched_barrier(0);                                                   \
    __builtin_amdgcn_s_barrier();                                                        \
  } while (0)

    for (int T = 0; T < nt; T += 2) {
        TILE8(0, T);
        TILE8(1, T + 1);
    }
#undef TILE8

    // ---- epilogue: route by n0 ----
    if (n0 >= 5120) {
#pragma unroll
        for (int i = 0; i < 8; ++i) {
            int gm = m0 + wm * 128 + i * 16 + hi * 4;
            int bb = gm >> 11, s = gm & (SS - 1);
#pragma unroll
            for (int jj = 0; jj < 4; ++jj) {
                int gn = (n0 - 5120) + wn * 64 + jj * 16 + lo;
                int hkv = gn >> 7, d = gn & 127;
                us4 o;
#pragma unroll
                for (int r = 0; r < 4; ++r) o[r] = f2bf(acc[i][jj][r]);
                *(us4*)(Vt_ + (((size_t)(bb * NKV + hkv) * DD + d) * SS + s)) = o;
            }
        }
    } else {
        u16* Cb;
        int cstride, cn0;
        if (n0 < 4096) { Cb = Qb_; cstride = NH * DD;  cn0 = n0; }
        else           { Cb = Kb_; cstride = NKV * DD; cn0 = n0 - 4096; }
#pragma unroll
        for (int i = 0; i < 8; ++i) {
            int gm = m0 + wm * 128 + i * 16 + hi * 4;
#pragma unroll
            for (int jj = 0; jj < 4; ++jj) {
                int gn = cn0 + wn * 64 + jj * 16 + lo;
#pragma unroll
                for (int r = 0; r < 4; ++r)
                    Cb[(size_t)(gm + r) * cstride + gn] = f2bf(acc[i][jj][r]);
            }
        }
    }
}

// ---------------------------------------------------------------------------
// GEMM (m97 recipe, 1D grid + XCD-bijective swizzle) — O-projection.
// ---------------------------------------------------------------------------
template<bool C_F32>
__global__ __launch_bounds__(256) void gemm2s_k(const u16* __restrict__ A,
                                                const u16* __restrict__ Bt,
                                                void* __restrict__ Cp,
                                                int M, int N, int K, int nbx)
{
    const int cpx = (int)gridDim.x >> 3;
    const int swz = (blockIdx.x & 7) * cpx + ((int)blockIdx.x >> 3);
    const int bx = swz % nbx, by = swz / nbx;
    const int m0 = by * 128, n0 = bx * 128;

    __shared__ u16 Al[128 * 64];
    __shared__ u16 Bl[128 * 64];
    const int tid = threadIdx.x;
    const int lane = tid & 63, w = tid >> 6;
    const int lo = lane & 15, hi = lane >> 4;
    const int wm = w >> 1, wn = w & 1;

    const int srow = w * 32 + (lane >> 3);
    const int sslot = (lane & 7) ^ (lane >> 3);
    const u16* Asrc = A + (size_t)(m0 + srow) * K + sslot * 8;
    const u16* Bsrc = Bt + (size_t)(n0 + srow) * K + sslot * 8;

    f32x4 acc[4][4] = {};

    for (int k0 = 0; k0 < K; k0 += 64) {
        __syncthreads();
#pragma unroll
        for (int t = 0; t < 4; ++t) {
            GLOAD16(Asrc + (size_t)t * 8 * K + k0, &Al[(w * 32 + t * 8) * 64]);
            GLOAD16(Bsrc + (size_t)t * 8 * K + k0, &Bl[(w * 32 + t * 8) * 64]);
        }
        __syncthreads();
#pragma unroll
        for (int c = 0; c < 2; ++c) {
            short8 af[4], bfv[4];
#pragma unroll
            for (int i = 0; i < 4; ++i) {
                int row = wm * 64 + i * 16 + lo;
                af[i] = *(const short8*)&Al[row * 64 + (((c * 4 + hi) ^ (lo & 7)) * 8)];
            }
#pragma unroll
            for (int j = 0; j < 4; ++j) {
                int row = wn * 64 + j * 16 + lo;
                bfv[j] = *(const short8*)&Bl[row * 64 + (((c * 4 + hi) ^ (lo & 7)) * 8)];
            }
#pragma unroll
            for (int i = 0; i < 4; ++i)
#pragma unroll
                for (int j = 0; j < 4; ++j)
                    acc[i][j] = MFMA16(af[i], bfv[j], acc[i][j]);
        }
    }

#pragma unroll
    for (int i = 0; i < 4; ++i) {
        int gm = m0 + wm * 64 + i * 16 + hi * 4;
#pragma unroll
        for (int j = 0; j < 4; ++j) {
            int gn = n0 + wn * 64 + j * 16 + lo;
#pragma unroll
            for (int r = 0; r < 4; ++r) {
                if constexpr (C_F32)
                    ((float*)Cp)[(size_t)(gm + r) * N + gn] = acc[i][j][r];
                else
                    ((u16*)Cp)[(size_t)(gm + r) * N + gn] = f2bf(acc[i][j][r]);
            }
        }
    }
}

// ---------------------------------------------------------------------------
// RoPE (rotate-half) on bf16 (B,S,nheads,D); scale folded into Q.
// ---------------------------------------------------------------------------
__global__ __launch_bounds__(256) void rope_k(u16* buf,
                                              const float* __restrict__ cosT,
                                              const float* __restrict__ sinT,
                                              int nheads, float scale)
{
    int idx = blockIdx.x * 256 + threadIdx.x;
    int total = BB * SS * nheads * 64;
    if (idx >= total) return;
    int d = idx & 63;
    int rem = idx >> 6;
    int hh = rem % nheads;
    int s = (rem / nheads) & (SS - 1);
    int bb = rem / (nheads * SS);
    size_t base = ((size_t)(bb * SS + s) * nheads + hh) * DD;
    float x0 = bf2f(buf[base + d]), x1 = bf2f(buf[base + d + 64]);
    float c = cosT[s * DD + d], sn = sinT[s * DD + d];
    buf[base + d]      = f2bf((x0 * c - x1 * sn) * scale);
    buf[base + d + 64] = f2bf((x0 * sn + x1 * c) * scale);
}

// ---------------------------------------------------------------------------
// P-exchange: 8 f32 P-values -> bf16 A-fragment (cvt_pk + shfl_xor(32)).
// ---------------------------------------------------------------------------
__device__ __forceinline__ short8 make_pa(float p0, float p1, float p2, float p3,
                                          float p4, float p5, float p6, float p7,
                                          int hi1)
{
    unsigned w0, w1, w2, w3;
    asm("v_cvt_pk_bf16_f32 %0, %1, %2" : "=v"(w0) : "v"(p0), "v"(p1));
    asm("v_cvt_pk_bf16_f32 %0, %1, %2" : "=v"(w1) : "v"(p2), "v"(p3));
    asm("v_cvt_pk_bf16_f32 %0, %1, %2" : "=v"(w2) : "v"(p4), "v"(p5));
    asm("v_cvt_pk_bf16_f32 %0, %1, %2" : "=v"(w3) : "v"(p6), "v"(p7));
    unsigned xw0 = (unsigned)__shfl_xor((int)w0, 32);
    unsigned xw1 = (unsigned)__shfl_xor((int)w1, 32);
    unsigned xw2 = (unsigned)__shfl_xor((int)w2, 32);
    unsigned xw3 = (unsigned)__shfl_xor((int)w3, 32);
    union { unsigned u[4]; short8 s; } cv;
    cv.u[0] = hi1 ? xw2 : w0;
    cv.u[1] = hi1 ? xw3 : w1;
    cv.u[2] = hi1 ? w2 : xw0;
    cv.u[3] = hi1 ? w3 : xw1;
    return cv.s;
}

// ---------------------------------------------------------------------------
// Flash attention v9 (verified): QBLK=256, 8 waves, 512 threads, all 512
// blocks resident, pair-balanced qt, XCD-chunk L2 locality.
// ---------------------------------------------------------------------------
__global__ __launch_bounds__(512, 2) void attn9_k(const u16* __restrict__ Qb,
                                                  const u16* __restrict__ Kb,
                                                  const u16* __restrict__ Vt,
                                                  u16* __restrict__ AO)
{
    const int wgid = blockIdx.x;
    const int k = wgid & 7;
    const int j = wgid >> 3;
    const int u = j & 31, v = j >> 5;
    const int qtb = u >> 3;
    const int qt = v ? 7 - qtb : qtb;
    const int h  = (k & 3) * 8 + (u & 7);
    const int b  = k >> 2;
    const int hkv = h >> 2;
    const int tid = threadIdx.x;
    const int w = tid >> 6, lane = tid & 63;
    const int l31 = lane & 31, hi1 = lane >> 5;
    const int qr0 = qt * 256 + w * 32;

    __shared__ u16 Kl[2][64 * 128];
    __shared__ u16 Vl[2][128 * 64];

    short8 qf[8];
    {
        const u16* qrow = Qb + ((size_t)(b * SS + qr0 + l31) * NH + h) * DD + hi1 * 8;
#pragma unroll
        for (int ks = 0; ks < 8; ++ks) qf[ks] = *(const short8*)(qrow + ks * 16);
    }

    const u16* kbase = Kb + ((size_t)b * SS * NKV + hkv) * DD;
    const u16* vbase = Vt + (size_t)(b * NKV + hkv) * DD * SS;

    f32x16 oacc[4] = {};
    float mreg = -INFINITY, lreg = 0.f;

    const int nkt = 4 * qt + 4;
    const int rk = lane >> 4, sk = lane & 15;
    const int rv = lane >> 3, sv = lane & 7;

#pragma unroll
    for (int i = 0; i < 2; ++i) {
        const int c = w * 2 + i;
        const int krow = c * 4 + rk;
        GLOAD16(kbase + (size_t)krow * (NKV * DD) + ((sk ^ (krow & 15)) * 8), &Kl[0][c * 512]);
        const int vrow = c * 8 + rv;
        GLOAD16(vbase + (size_t)vrow * SS + ((sv ^ (vrow & 7)) * 8), &Vl[0][c * 512]);
    }
    __syncthreads();

    int buf = 0;
    for (int kt = 0; kt < nkt; ++kt) {
        const int kv0 = kt * 64;
        if (kt + 1 < nkt) {
            const int kv1 = kv0 + 64;
#pragma unroll
            for (int i = 0; i < 2; ++i) {
                const int c = w * 2 + i;
                const int krow = c * 4 + rk;
                GLOAD16(kbase + (size_t)(kv1 + krow) * (NKV * DD) + ((sk ^ (krow & 15)) * 8),
                        &Kl[buf ^ 1][c * 512]);
                const int vrow = c * 8 + rv;
                GLOAD16(vbase + (size_t)vrow * SS + kv1 + ((sv ^ (vrow & 7)) * 8),
                        &Vl[buf ^ 1][c * 512]);
            }
        }

        if (kv0 <= qr0 + 31) {
            const u16* Kc = Kl[buf];
            const u16* Vc = Vl[buf];

            f32x16 s0 = {}, s1 = {};
            __builtin_amdgcn_s_setprio(1);
#pragma unroll
            for (int ks = 0; ks < 8; ++ks) {
                const int slot = (((2 * ks + hi1) ^ sk) * 8);
                short8 kf0 = *(const short8*)&Kc[l31 * 128 + slot];
                s0 = MFMA32(kf0, qf[ks], s0);
                short8 kf1 = *(const short8*)&Kc[(32 + l31) * 128 + slot];
                s1 = MFMA32(kf1, qf[ks], s1);
            }
            __builtin_amdgcn_s_setprio(0);

            const int qab = qr0 + l31;
            if (kv0 + 63 > qr0) {
#pragma unroll
                for (int r = 0; r < 16; ++r) {
                    const int off = (r & 3) + 8 * (r >> 2) + 4 * hi1;
                    if (kv0 + off > qab)      s0[r] = -INFINITY;
                    if (kv0 + 32 + off > qab) s1[r] = -INFINITY;
                }
            }
            float m0 = fmaxf(s0[0], s1[0]), m1 = fmaxf(s0[1], s1[1]);
            float m2 = fmaxf(s0[2], s1[2]), m3 = fmaxf(s0[3], s1[3]);
#pragma unroll
            for (int r = 4; r < 16; r += 4) {
                m0 = fmaxf(m0, fmaxf(s0[r],     s1[r]));
                m1 = fmaxf(m1, fmaxf(s0[r + 1], s1[r + 1]));
                m2 = fmaxf(m2, fmaxf(s0[r + 2], s1[r + 2]));
                m3 = fmaxf(m3, fmaxf(s0[r + 3], s1[r + 3]));
            }
            float mx = fmaxf(fmaxf(m0, m1), fmaxf(m2, m3));
            mx = fmaxf(mx, __shfl_xor(mx, 32));

            if (__any(mx > mreg + 8.0f)) {
                const float nm = fmaxf(mreg, mx);
                const float al = exp2f(mreg - nm);
                mreg = nm;
                lreg *= al;
#pragma unroll
                for (int r = 0; r < 16; ++r) {
                    const float ar = __shfl(al, (r & 3) + 8 * (r >> 2) + 4 * hi1);
#pragma unroll
                    for (int db = 0; db < 4; ++db) oacc[db][r] *= ar;
                }
            }

#pragma unroll
            for (int r = 0; r < 16; ++r) {
                s0[r] = exp2f(s0[r] - mreg);
                s1[r] = exp2f(s1[r] - mreg);
            }
            float sa = 0.f, sb = 0.f, sc_ = 0.f, sd = 0.f;
#pragma unroll
            for (int r = 0; r < 16; r += 4) {
                sa  += s0[r]     + s1[r];
                sb  += s0[r + 1] + s1[r + 1];
                sc_ += s0[r + 2] + s1[r + 2];
                sd  += s0[r + 3] + s1[r + 3];
            }
            lreg += (sa + sb) + (sc_ + sd);

            short8 pa0 = make_pa(s0[0], s0[1], s0[2],  s0[3],  s0[4],  s0[5],  s0[6],  s0[7],  hi1);
            short8 pa1 = make_pa(s0[8], s0[9], s0[10], s0[11], s0[12], s0[13], s0[14], s0[15], hi1);
            short8 pa2 = make_pa(s1[0], s1[1], s1[2],  s1[3],  s1[4],  s1[5],  s1[6],  s1[7],  hi1);
            short8 pa3 = make_pa(s1[8], s1[9], s1[10], s1[11], s1[12], s1[13], s1[14], s1[15], hi1);

            __builtin_amdgcn_s_setprio(1);
#pragma unroll
            for (int db = 0; db < 4; ++db) {
                const int vr = (db * 32 + l31) * 64;
                short8 vf0 = *(const short8*)&Vc[vr + (((0 + hi1) ^ sv) * 8)];
                oacc[db] = MFMA32(pa0, vf0, oacc[db]);
                short8 vf1 = *(const short8*)&Vc[vr + (((2 + hi1) ^ sv) * 8)];
                oacc[db] = MFMA32(pa1, vf1, oacc[db]);
                short8 vf2 = *(const short8*)&Vc[vr + (((4 + hi1) ^ sv) * 8)];
                oacc[db] = MFMA32(pa2, vf2, oacc[db]);
                short8 vf3 = *(const short8*)&Vc[vr + (((6 + hi1) ^ sv) * 8)];
                oacc[db] = MFMA32(pa3, vf3, oacc[db]);
            }
            __builtin_amdgcn_s_setprio(0);
        }
        __syncthreads();
        buf ^= 1;
    }

    const float lf = lreg + __shfl_xor(lreg, 32);
#pragma unroll
    for (int r = 0; r < 16; ++r) {
        const int qrw = (r & 3) + 8 * (r >> 2) + 4 * hi1;
        const float linv = 1.0f / __shfl(lf, qrw);
        u16* orow = AO + ((size_t)(b * SS + qr0 + qrw) * NH + h) * DD + l31;
#pragma unroll
        for (int db = 0; db < 4; ++db)
            orow[db * 32] = f2bf(oacc[db][r] * linv);
    }
}

// ===========================================================================
// FALLBACK (round-1 proven path, used only if ws_size is too small)
// ===========================================================================
template<bool A_BF16, bool C_F32>
__global__ __launch_bounds__(256) void gemm_k(const void* __restrict__ Ap,
                                              const float* __restrict__ Bp,
                                              void* __restrict__ Cp,
                                              int M, int N, int K)
{
    __shared__ u16 Asm[128 * 40];
    __shared__ u16 Bsm[128 * 40];
    const int tid  = threadIdx.x;
    const int lane = tid & 63, wid = tid >> 6;
    const int lo = lane & 15, hi = lane >> 4;
    const int wm = wid >> 1, wn = wid & 1;
    const int m0 = blockIdx.y * 128, n0 = blockIdx.x * 128;
    f32x4 acc[4][4] = {};
    const int nkt = K >> 5;
    for (int kt = 0; kt < nkt; ++kt) {
        const int k0 = kt << 5;
        __syncthreads();
        if constexpr (A_BF16) {
            const u16* A = (const u16*)Ap;
#pragma unroll
            for (int it = 0; it < 4; ++it) {
                int f = it * 256 + tid;
                int row = f >> 3, kg = (f & 7) * 4;
                us4 v = *(const us4*)(A + (size_t)(m0 + row) * K + k0 + kg);
#pragma unroll
                for (int j = 0; j < 4; ++j) Asm[row * 40 + kg + j] = v[j];
            }
        } else {
            const float* A = (const float*)Ap;
#pragma unroll
            for (int it = 0; it < 4; ++it) {
                int f = it * 256 + tid;
                int row = f >> 3, kg = (f & 7) * 4;
                f32x4 v = *(const f32x4*)(A + (size_t)(m0 + row) * K + k0 + kg);
#pragma unroll
                for (int j = 0; j < 4; ++j) Asm[row * 40 + kg + j] = f2bf(v[j]);
            }
        }
#pragma unroll
        for (int it = 0; it < 4; ++it) {
            int f = it * 256 + tid;
            int kr = f >> 5, cg = (f & 31) * 4;
            f32x4 v = *(const f32x4*)(Bp + (size_t)(k0 + kr) * N + n0 + cg);
#pragma unroll
            for (int j = 0; j < 4; ++j) Bsm[(cg + j) * 40 + kr] = f2bf(v[j]);
        }
        __syncthreads();
        short8 af[4], bfr[4];
#pragma unroll
        for (int i = 0; i < 4; ++i)
            af[i] = *(const short8*)&Asm[(wm * 64 + i * 16 + lo) * 40 + hi * 8];
#pragma unroll
        for (int j = 0; j < 4; ++j)
            bfr[j] = *(const short8*)&Bsm[(wn * 64 + j * 16 + lo) * 40 + hi * 8];
#pragma unroll
        for (int i = 0; i < 4; ++i)
#pragma unroll
            for (int j = 0; j < 4; ++j)
                acc[i][j] = MFMA16(af[i], bfr[j], acc[i][j]);
    }
#pragma unroll
    for (int i = 0; i < 4; ++i) {
        int gm = m0 + wm * 64 + i * 16 + hi * 4;
#pragma unroll
        for (int j = 0; j < 4; ++j) {
            int gn = n0 + wn * 64 + j * 16 + lo;
#pragma unroll
            for (int r = 0; r < 4; ++r) {
                if constexpr (C_F32)
                    ((float*)Cp)[(size_t)(gm + r) * N + gn] = acc[i][j][r];
                else
                    ((u16*)Cp)[(size_t)(gm + r) * N + gn] = f2bf(acc[i][j][r]);
            }
        }
    }
}

__global__ __launch_bounds__(64) void attn_k(const u16* __restrict__ Qb,
                                             const u16* __restrict__ Kb,
                                             const u16* __restrict__ Vb,
                                             u16* __restrict__ AO)
{
    const int blk = blockIdx.x;
    const int qt = blk & (SS / 16 - 1);
    const int h  = (blk >> 7) & (NH - 1);
    const int b  = blk >> 12;
    const int hkv = h >> 2;
    const int lane = threadIdx.x;
    const int lo = lane & 15, hi = lane >> 4;
    const int qbase = qt * 16;
    __shared__ float sc[16][32];
    __shared__ u16 vt[128 * 40];
    short8 qf[4];
    const u16* qrow = Qb + ((size_t)(b * SS + qbase + lo) * NH + h) * DD;
#pragma unroll
    for (int c = 0; c < 4; ++c) qf[c] = *(const short8*)(qrow + c * 32 + hi * 8);
    f32x4 oacc[8] = {};
    float m[4] = {-INFINITY, -INFINITY, -INFINITY, -INFINITY};
    float l[4] = {0.f, 0.f, 0.f, 0.f};
    const int nkt = (qbase + 16 + 31) >> 5;
    for (int kt = 0; kt < nkt; ++kt) {
        const int kv0 = kt << 5;
        f32x4 s0 = {}, s1 = {};
        const u16* kb0 = Kb + ((size_t)(b * SS + kv0) * NKV + hkv) * DD;
#pragma unroll
        for (int c = 0; c < 4; ++c) {
            short8 k0f = *(const short8*)(kb0 + (size_t)lo * (NKV * DD) + c * 32 + hi * 8);
            short8 k1f = *(const short8*)(kb0 + (size_t)(lo + 16) * (NKV * DD) + c * 32 + hi * 8);
            s0 = MFMA16(qf[c], k0f, s0);
            s1 = MFMA16(qf[c], k1f, s1);
        }
#pragma unroll
        for (int i = 0; i < 8; ++i) {
            int g = i * 64 + lane;
            int row = g >> 4, dg = (g & 15) * 8;
            short8 vv = *(const short8*)(Vb + ((size_t)(b * SS + kv0 + row) * NKV + hkv) * DD + dg);
#pragma unroll
            for (int j = 0; j < 8; ++j) vt[(dg + j) * 40 + row] = (u16)vv[j];
        }
        float alpha[4];
#pragma unroll
        for (int r = 0; r < 4; ++r) {
            int qrowi = qbase + hi * 4 + r;
            float v0 = s0[r]; if (kv0 + lo > qrowi)      v0 = -INFINITY;
            float v1 = s1[r]; if (kv0 + 16 + lo > qrowi) v1 = -INFINITY;
            float mx = fmaxf(v0, v1);
#pragma unroll
            for (int off = 1; off < 16; off <<= 1) mx = fmaxf(mx, __shfl_xor(mx, off, 64));
            float nm = fmaxf(m[r], mx);
            float a = __expf(m[r] - nm);
            v0 = __expf(v0 - nm);
            v1 = __expf(v1 - nm);
            float ps = v0 + v1;
#pragma unroll
            for (int off = 1; off < 16; off <<= 1) ps += __shfl_xor(ps, off, 64);
            l[r] = l[r] * a + ps;
            m[r] = nm;
            alpha[r] = a;
            sc[hi * 4 + r][lo] = v0;
            sc[hi * 4 + r][16 + lo] = v1;
        }
#pragma unroll
        for (int n = 0; n < 8; ++n)
#pragma unroll
            for (int r = 0; r < 4; ++r) oacc[n][r] *= alpha[r];
        __syncthreads();
        f32x4 p0 = *(const f32x4*)&sc[lo][hi * 8];
        f32x4 p1 = *(const f32x4*)&sc[lo][hi * 8 + 4];
        short8 pf;
#pragma unroll
        for (int j = 0; j < 4; ++j) {
            pf[j]     = (short)f2bf(p0[j]);
            pf[4 + j] = (short)f2bf(p1[j]);
        }
#pragma unroll
        for (int n = 0; n < 8; ++n) {
            short8 vf = *(const short8*)&vt[(n * 16 + lo) * 40 + hi * 8];
            oacc[n] = MFMA16(pf, vf, oacc[n]);
        }
        __syncthreads();
    }
#pragma unroll
    for (int n = 0; n < 8; ++n) {
#pragma unroll
        for (int r = 0; r < 4; ++r) {
            size_t idx = ((size_t)(b * SS + qbase + hi * 4 + r) * NH + h) * DD + n * 16 + lo;
            AO[idx] = f2bf(oacc[n][r] / l[r]);
        }
    }
}

// ---------------------------------------------------------------------------
extern "C" void kernel_launch(void* const* d_in, const int* in_sizes, int n_in,
                              void* d_out, int out_size, void* d_ws, size_t ws_size,
                              hipStream_t stream) {
    const float* hs   = (const float*)d_in[0];
    const float* sinT = (const float*)d_in[1];
    const float* cosT = (const float*)d_in[2];
    const float* Wq   = (const float*)d_in[3];
    const float* Wk   = (const float*)d_in[4];
    const float* Wv   = (const float*)d_in[5];
    const float* Wo   = (const float*)d_in[6];
    float* out = (float*)d_out;
    const int M = BB * SS;
    u16* ws = (u16*)d_ws;

    const size_t NEED = 109051904;  // bytes (54,525,952 u16)
    if (ws_size >= NEED) {
        u16* Qb   = ws;                 // [0, 16777216)
        u16* Kb   = ws + 16777216;      // [16777216, 20971520)
        u16* Vt   = ws + 25165824;      // [25165824, 29360128)
        u16* Wcat = ws + 29360128;      // [29360128, 41943040)  6144x2048
        u16* hsb  = ws + 41943040;      // [41943040, 50331648)
        u16* Wot  = Wcat;               // reuse after QKV gemm
        u16* AO   = ws + 37748736;      // [37748736, 54525952)  after Wot transpose

        cvt_k<<<4096, 256, 0, stream>>>(hs, hsb, (M * HID) / 8);
        // Wcat rows: [0,4096)=Wq^T, [4096,5120)=Wk^T, [5120,6144)=Wv^T
        tw_k<<<dim3(4096 / 32, 2048 / 32), 256, 0, stream>>>(Wq, Wcat, HID, NH * DD);
        tw_k<<<dim3(1024 / 32, 2048 / 32), 256, 0, stream>>>(Wk, Wcat + (size_t)4096 * 2048, HID, NKV * DD);
        tw_k<<<dim3(1024 / 32, 2048 / 32), 256, 0, stream>>>(Wv, Wcat + (size_t)5120 * 2048, HID, NKV * DD);

        // fused QKV projection (256^2 deep pipeline + m201 double-barrier)
        gemm8qkv_k<<<384, 512, 0, stream>>>(hsb, Wcat, Qb, Kb, Vt);

        // Q scale = (1/sqrt(128)) * log2(e)  [softmax in exp2 domain]
        rope_k<<<(BB * SS * NH * 64 + 255) / 256, 256, 0, stream>>>(Qb, cosT, sinT, NH, 0.12751744f);
        rope_k<<<(BB * SS * NKV * 64 + 255) / 256, 256, 0, stream>>>(Kb, cosT, sinT, NKV, 1.0f);
        tw_k<<<dim3(2048 / 32, 4096 / 32), 256, 0, stream>>>(Wo, Wot, NH * DD, HID);

        attn9_k<<<SS / 256 * NH * BB, 512, 0, stream>>>(Qb, Kb, Vt, AO);

        // output projection (proven 2-phase 128^2, 512 blocks)
        gemm2s_k<true><<<512, 256, 0, stream>>>(AO, Wot, out, M, HID, NH * DD, HID / 128);
    } else {
        u16* Qb   = ws;
        u16* Kbuf = Qb   + (size_t)BB * SS * NH * DD;
        u16* Vbuf = Kbuf + (size_t)BB * SS * NKV * DD;
        u16* AO   = Vbuf + (size_t)BB * SS * NKV * DD;

        gemm_k<false, false><<<dim3((NH * DD) / 128, M / 128), 256, 0, stream>>>(hs, Wq, Qb, M, NH * DD, HID);
        gemm_k<false, false><<<dim3((NKV * DD) / 128, M / 128), 256, 0, stream>>>(hs, Wk, Kbuf, M, NKV * DD, HID);
        gemm_k<false, false><<<dim3((NKV * DD) / 128, M / 128), 256, 0, stream>>>(hs, Wv, Vbuf, M, NKV * DD, HID);
        rope_k<<<(BB * SS * NH * 64 + 255) / 256, 256, 0, stream>>>(Qb, cosT, sinT, NH, 0.08838834764831845f);
        rope_k<<<(BB * SS * NKV * 64 + 255) / 256, 256, 0, stream>>>(Kbuf, cosT, sinT, NKV, 1.0f);
        attn_k<<<BB * NH * (SS / 16), 64, 0, stream>>>(Qb, Kbuf, Vbuf, AO);
        gemm_k<true, true><<<dim3(HID / 128, M / 128), 256, 0, stream>>>(AO, Wo, out, M, HID, NH * DD);
    }
}

// Round 14
// 352.249 us; speedup vs baseline: 1.0377x; 1.0221x over previous
//
#include <hip/hip_runtime.h>
#include <hip/hip_bf16.h>
#include <math.h>

#define BB 2
#define SS 2048
#define HID 2048
#define NH 32
#define NKV 8
#define DD 128

typedef unsigned short u16;
typedef __attribute__((ext_vector_type(8))) short short8;
typedef __attribute__((ext_vector_type(4))) float f32x4;
typedef __attribute__((ext_vector_type(16))) float f32x16;
typedef __attribute__((ext_vector_type(4))) unsigned short us4;

__device__ __forceinline__ u16 f2bf(float f) {
    unsigned int u = __float_as_uint(f);
    u += 0x7fff + ((u >> 16) & 1);
    return (u16)(u >> 16);
}
__device__ __forceinline__ float bf2f(u16 h) {
    return __uint_as_float(((unsigned int)h) << 16);
}

#define GLOAD16(gp, lp) __builtin_amdgcn_global_load_lds(                      \
    (const __attribute__((address_space(1))) void*)(gp),                       \
    (__attribute__((address_space(3))) void*)(lp), 16, 0, 0)

#define MFMA32(a, b, c) __builtin_amdgcn_mfma_f32_32x32x16_bf16(a, b, c, 0, 0, 0)
#define MFMA16(a, b, c) __builtin_amdgcn_mfma_f32_16x16x32_bf16(a, b, c, 0, 0, 0)

// ---------------------------------------------------------------------------
// cvt: fp32 -> bf16 elementwise (8 elems/thread)
// ---------------------------------------------------------------------------
__global__ __launch_bounds__(256) void cvt_k(const float* __restrict__ in,
                                             u16* __restrict__ out, int n8)
{
    int i = blockIdx.x * 256 + threadIdx.x;
    if (i >= n8) return;
    f32x4 a = ((const f32x4*)in)[i * 2];
    f32x4 b = ((const f32x4*)in)[i * 2 + 1];
    short8 o;
#pragma unroll
    for (int j = 0; j < 4; ++j) { o[j] = (short)f2bf(a[j]); o[4 + j] = (short)f2bf(b[j]); }
    ((short8*)out)[i] = o;
}

// ---------------------------------------------------------------------------
// transpose + convert: fp32 in[R][C] -> bf16 out[C][R]. 32x32 tiles.
// ---------------------------------------------------------------------------
__global__ __launch_bounds__(256) void tw_k(const float* __restrict__ in,
                                            u16* __restrict__ out, int R, int C)
{
    __shared__ float t[32][33];
    const int tc = blockIdx.x * 32, tr = blockIdx.y * 32;
    const int r = threadIdx.x >> 3, c4 = (threadIdx.x & 7) * 4;
    f32x4 v = *(const f32x4*)(in + (size_t)(tr + r) * C + tc + c4);
#pragma unroll
    for (int j = 0; j < 4; ++j) t[r][c4 + j] = v[j];
    __syncthreads();
    us4 o;
#pragma unroll
    for (int j = 0; j < 4; ++j) o[j] = f2bf(t[c4 + j][r]);
    *(us4*)(out + (size_t)(tc + r) * R + tr + c4) = o;
}

// ---------------------------------------------------------------------------
// V transpose (fallback-path only): Vb (B,S,HKV,D) -> Vt (B,HKV,D,S).
// ---------------------------------------------------------------------------
__global__ __launch_bounds__(256) void vtr_k(const u16* __restrict__ Vb,
                                             u16* __restrict__ Vt)
{
    __shared__ u16 t[64][72];
    const int s0 = blockIdx.x * 64, d0 = blockIdx.y * 64;
    const int b = blockIdx.z >> 3, hkv = blockIdx.z & 7;
    const int tid = threadIdx.x;
    const int rr = tid >> 3, cc = (tid & 7) * 8;
#pragma unroll
    for (int it = 0; it < 2; ++it) {
        int row = rr + it * 32;
        short8 v = *(const short8*)(Vb + ((size_t)(b * SS + s0 + row) * NKV + hkv) * DD + d0 + cc);
#pragma unroll
        for (int j = 0; j < 8; ++j) t[row][cc + j] = (u16)v[j];
    }
    __syncthreads();
#pragma unroll
    for (int it = 0; it < 2; ++it) {
        int dr = rr + it * 32;
        short8 o;
#pragma unroll
        for (int j = 0; j < 8; ++j) o[j] = (short)t[cc + j][dr];
        *(short8*)(Vt + ((size_t)(b * NKV + hkv) * DD + d0 + dr) * SS + s0 + cc) = o;
    }
}

// ---------------------------------------------------------------------------
// QKV projection GEMM (round-11 verified, 124us): 256x256 tile, BK=64,
// 8 waves, deep pipeline (counted vmcnt(8), raw s_barrier, 4 phases/tile,
// 2-tile lookahead). Slot(h of tile T) = (2T+h)&3. Phases p0/p1: all
// ds_reads + 16 MFMA each; p2: MFMA + A-stage T+2; p3: MFMA + B-stage T+2 +
// vmcnt(8). Every phase ends lgkmcnt(0)+sched_barrier+s_barrier -> slot
// reads complete >=1 barrier before the replacement load is issued.
// Epilogue routes cols: [0,4096)->Qb, [4096,5120)->Kb, [5120,6144)->Vt^T.
// ---------------------------------------------------------------------------
__global__ __launch_bounds__(512, 2) void gemm8qkv_k(const u16* __restrict__ A,
                                                     const u16* __restrict__ Bt,
                                                     u16* __restrict__ Qb_,
                                                     u16* __restrict__ Kb_,
                                                     u16* __restrict__ Vt_)
{
    const int K = HID;                         // 2048, nt = 32
    const int k8 = blockIdx.x & 7;
    const int j  = (int)blockIdx.x >> 3;       // 0..47
    const int bx = j >> 1, by = k8 * 2 + (j & 1);
    const int m0 = by * 256, n0 = bx * 256;

    __shared__ u16 Asl[4][128 * 64];
    __shared__ u16 Bsl[4][128 * 64];

    const int tid = threadIdx.x;
    const int w = tid >> 6, lane = tid & 63;
    const int wm = w >> 2, wn = w & 3;
    const int lo = lane & 15, hi = lane >> 4;
    const int brow0 = (wn & 1) * 64;

    const int srow8 = lane >> 3;
    const int skk = ((lane & 7) ^ srow8) * 8;
    const u16* As = A + (size_t)(m0 + w * 16 + srow8) * K + skk;
    const u16* Bs = Bt + (size_t)(n0 + w * 16 + srow8) * K + skk;

#define SA8(slot, half, kof) do {                                                        \
    GLOAD16(As + (size_t)((half) * 128) * K + (kof), &Asl[slot][(w * 16) * 64]);         \
    GLOAD16(As + (size_t)((half) * 128 + 8) * K + (kof), &Asl[slot][(w * 16 + 8) * 64]); \
  } while (0)
#define SB8(slot, half, kof) do {                                                        \
    GLOAD16(Bs + (size_t)((half) * 128) * K + (kof), &Bsl[slot][(w * 16) * 64]);         \
    GLOAD16(Bs + (size_t)((half) * 128 + 8) * K + (kof), &Bsl[slot][(w * 16 + 8) * 64]); \
  } while (0)
#define PHASE_END() do {                                       \
    asm volatile("s_waitcnt lgkmcnt(0)" ::: "memory");         \
    __builtin_amdgcn_sched_barrier(0);                         \
    __builtin_amdgcn_s_barrier();                              \
  } while (0)

    f32x4 acc[8][4] = {};
    const int nt = K >> 6;                    // 32

    // ---- prologue: stage tiles 0 (slots 0,1) and 1 (slots 2,3) ----
    SA8(0, 0, 0);  SA8(1, 1, 0);  SB8(0, 0, 0);  SB8(1, 1, 0);
    SA8(2, 0, 64); SA8(3, 1, 64); SB8(2, 0, 64); SB8(3, 1, 64);
    asm volatile("s_waitcnt vmcnt(8)" ::: "memory");   // tile0 landed
    __builtin_amdgcn_s_barrier();

#define TILE8(P, T) do {                                                                 \
    const u16* Apan = Asl[(P) * 2 + wm];                                                 \
    const u16* Bpan = Bsl[(P) * 2 + (wn >> 1)];                                          \
    short8 afr[2][8]; short8 bfr[2][4];                                                  \
    /* ---- phase 0: read A[0..3],B[0..1] frags; MFMA i0-3 x j0-1 ---- */                \
    _Pragma("unroll") for (int c = 0; c < 2; ++c) {                                      \
      _Pragma("unroll") for (int i = 0; i < 4; ++i)                                      \
        afr[c][i] = *(const short8*)&Apan[(i * 16 + lo) * 64 + (((c * 4 + hi) ^ (lo & 7)) * 8)]; \
      _Pragma("unroll") for (int jj = 0; jj < 2; ++jj)                                   \
        bfr[c][jj] = *(const short8*)&Bpan[(brow0 + jj * 16 + lo) * 64 + (((c * 4 + hi) ^ (lo & 7)) * 8)]; \
    }                                                                                    \
    __builtin_amdgcn_s_setprio(1);                                                       \
    _Pragma("unroll") for (int i = 0; i < 4; ++i)                                        \
      _Pragma("unroll") for (int jj = 0; jj < 2; ++jj) {                                 \
        acc[i][jj] = MFMA16(afr[0][i], bfr[0][jj], acc[i][jj]);                          \
        acc[i][jj] = MFMA16(afr[1][i], bfr[1][jj], acc[i][jj]);                          \
      }                                                                                  \
    __builtin_amdgcn_s_setprio(0);                                                       \
    PHASE_END();                                                                         \
    /* ---- phase 1: read A[4..7],B[2..3]; MFMA i0-3 x j2-3 ---- */                      \
    _Pragma("unroll") for (int c = 0; c < 2; ++c) {                                      \
      _Pragma("unroll") for (int i = 4; i < 8; ++i)                                      \
        afr[c][i] = *(const short8*)&Apan[(i * 16 + lo) * 64 + (((c * 4 + hi) ^ (lo & 7)) * 8)]; \
      _Pragma("unroll") for (int jj = 2; jj < 4; ++jj)                                   \
        bfr[c][jj] = *(const short8*)&Bpan[(brow0 + jj * 16 + lo) * 64 + (((c * 4 + hi) ^ (lo & 7)) * 8)]; \
    }                                                                                    \
    __builtin_amdgcn_s_setprio(1);                                                       \
    _Pragma("unroll") for (int i = 0; i < 4; ++i)                                        \
      _Pragma("unroll") for (int jj = 2; jj < 4; ++jj) {                                 \
        acc[i][jj] = MFMA16(afr[0][i], bfr[0][jj], acc[i][jj]);                          \
        acc[i][jj] = MFMA16(afr[1][i], bfr[1][jj], acc[i][jj]);                          \
      }                                                                                  \
    __builtin_amdgcn_s_setprio(0);                                                       \
    PHASE_END();                                                                         \
    /* ---- phase 2: MFMA i4-7 x j0-1; issue A-stage of T+2 ---- */                      \
    __builtin_amdgcn_s_setprio(1);                                                       \
    _Pragma("unroll") for (int i = 4; i < 8; ++i)                                        \
      _Pragma("unroll") for (int jj = 0; jj < 2; ++jj) {                                 \
        acc[i][jj] = MFMA16(afr[0][i], bfr[0][jj], acc[i][jj]);                          \
        acc[i][jj] = MFMA16(afr[1][i], bfr[1][jj], acc[i][jj]);                          \
      }                                                                                  \
    __builtin_amdgcn_s_setprio(0);                                                       \
    if ((T) + 2 < nt) {                                                                  \
      SA8((P) * 2 + 0, 0, ((T) + 2) * 64); SA8((P) * 2 + 1, 1, ((T) + 2) * 64);          \
    }                                                                                    \
    PHASE_END();                                                                         \
    /* ---- phase 3: MFMA i4-7 x j2-3; issue B-stage of T+2; counted vmcnt ---- */       \
    __builtin_amdgcn_s_setprio(1);                                                       \
    _Pragma("unroll") for (int i = 4; i < 8; ++i)                                        \
      _Pragma("unroll") for (int jj = 2; jj < 4; ++jj) {                                 \
        acc[i][jj] = MFMA16(afr[0][i], bfr[0][jj], acc[i][jj]);                          \
        acc[i][jj] = MFMA16(afr[1][i], bfr[1][jj], acc[i][jj]);                          \
      }                                                                                  \
    __builtin_amdgcn_s_setprio(0);                                                       \
    if ((T) + 2 < nt) {                                                                  \
      SB8((P) * 2 + 0, 0, ((T) + 2) * 64); SB8((P) * 2 + 1, 1, ((T) + 2) * 64);          \
      asm volatile("s_waitcnt vmcnt(8)" ::: "memory");                                   \
    } else {                                                                             \
      asm volatile("s_waitcnt vmcnt(0)" ::: "memory");                                   \
    }                                                                                    \
    asm volatile("s_waitcnt lgkmcnt(0)" ::: "memory");                                   \
    __builtin_amdgcn_sched_barrier(0);                                                   \
    __builtin_amdgcn_s_barrier();                                                        \
  } while (0)

    for (int T = 0; T < nt; T += 2) {
        TILE8(0, T);
        TILE8(1, T + 1);
    }
#undef TILE8

    // ---- epilogue: route by n0 ----
    if (n0 >= 5120) {
#pragma unroll
        for (int i = 0; i < 8; ++i) {
            int gm = m0 + wm * 128 + i * 16 + hi * 4;
            int bb = gm >> 11, s = gm & (SS - 1);
#pragma unroll
            for (int jj = 0; jj < 4; ++jj) {
                int gn = (n0 - 5120) + wn * 64 + jj * 16 + lo;
                int hkv = gn >> 7, d = gn & 127;
                us4 o;
#pragma unroll
                for (int r = 0; r < 4; ++r) o[r] = f2bf(acc[i][jj][r]);
                *(us4*)(Vt_ + (((size_t)(bb * NKV + hkv) * DD + d) * SS + s)) = o;
            }
        }
    } else {
        u16* Cb;
        int cstride, cn0;
        if (n0 < 4096) { Cb = Qb_; cstride = NH * DD;  cn0 = n0; }
        else           { Cb = Kb_; cstride = NKV * DD; cn0 = n0 - 4096; }
#pragma unroll
        for (int i = 0; i < 8; ++i) {
            int gm = m0 + wm * 128 + i * 16 + hi * 4;
#pragma unroll
            for (int jj = 0; jj < 4; ++jj) {
                int gn = cn0 + wn * 64 + jj * 16 + lo;
#pragma unroll
                for (int r = 0; r < 4; ++r)
                    Cb[(size_t)(gm + r) * cstride + gn] = f2bf(acc[i][jj][r]);
            }
        }
    }
}

// ---------------------------------------------------------------------------
// GEMM (m97 recipe, 1D grid + XCD-bijective swizzle) — O-projection.
// ---------------------------------------------------------------------------
template<bool C_F32>
__global__ __launch_bounds__(256) void gemm2s_k(const u16* __restrict__ A,
                                                const u16* __restrict__ Bt,
                                                void* __restrict__ Cp,
                                                int M, int N, int K, int nbx)
{
    const int cpx = (int)gridDim.x >> 3;
    const int swz = (blockIdx.x & 7) * cpx + ((int)blockIdx.x >> 3);
    const int bx = swz % nbx, by = swz / nbx;
    const int m0 = by * 128, n0 = bx * 128;

    __shared__ u16 Al[128 * 64];
    __shared__ u16 Bl[128 * 64];
    const int tid = threadIdx.x;
    const int lane = tid & 63, w = tid >> 6;
    const int lo = lane & 15, hi = lane >> 4;
    const int wm = w >> 1, wn = w & 1;

    const int srow = w * 32 + (lane >> 3);
    const int sslot = (lane & 7) ^ (lane >> 3);
    const u16* Asrc = A + (size_t)(m0 + srow) * K + sslot * 8;
    const u16* Bsrc = Bt + (size_t)(n0 + srow) * K + sslot * 8;

    f32x4 acc[4][4] = {};

    for (int k0 = 0; k0 < K; k0 += 64) {
        __syncthreads();
#pragma unroll
        for (int t = 0; t < 4; ++t) {
            GLOAD16(Asrc + (size_t)t * 8 * K + k0, &Al[(w * 32 + t * 8) * 64]);
            GLOAD16(Bsrc + (size_t)t * 8 * K + k0, &Bl[(w * 32 + t * 8) * 64]);
        }
        __syncthreads();
#pragma unroll
        for (int c = 0; c < 2; ++c) {
            short8 af[4], bfv[4];
#pragma unroll
            for (int i = 0; i < 4; ++i) {
                int row = wm * 64 + i * 16 + lo;
                af[i] = *(const short8*)&Al[row * 64 + (((c * 4 + hi) ^ (lo & 7)) * 8)];
            }
#pragma unroll
            for (int j = 0; j < 4; ++j) {
                int row = wn * 64 + j * 16 + lo;
                bfv[j] = *(const short8*)&Bl[row * 64 + (((c * 4 + hi) ^ (lo & 7)) * 8)];
            }
#pragma unroll
            for (int i = 0; i < 4; ++i)
#pragma unroll
                for (int j = 0; j < 4; ++j)
                    acc[i][j] = MFMA16(af[i], bfv[j], acc[i][j]);
        }
    }

#pragma unroll
    for (int i = 0; i < 4; ++i) {
        int gm = m0 + wm * 64 + i * 16 + hi * 4;
#pragma unroll
        for (int j = 0; j < 4; ++j) {
            int gn = n0 + wn * 64 + j * 16 + lo;
#pragma unroll
            for (int r = 0; r < 4; ++r) {
                if constexpr (C_F32)
                    ((float*)Cp)[(size_t)(gm + r) * N + gn] = acc[i][j][r];
                else
                    ((u16*)Cp)[(size_t)(gm + r) * N + gn] = f2bf(acc[i][j][r]);
            }
        }
    }
}

// ---------------------------------------------------------------------------
// RoPE (rotate-half), Q and K in ONE launch. Q scaled by 1/sqrt(D)*log2e.
// ---------------------------------------------------------------------------
__global__ __launch_bounds__(256) void rope2_k(u16* __restrict__ Qb,
                                               u16* __restrict__ Kb,
                                               const float* __restrict__ cosT,
                                               const float* __restrict__ sinT)
{
    int idx = blockIdx.x * 256 + threadIdx.x;
    const int totQ = BB * SS * NH * 64;
    const int totK = BB * SS * NKV * 64;
    u16* buf;
    int nheads;
    float scale;
    if (idx < totQ) {
        buf = Qb; nheads = NH; scale = 0.12751744f;   // (1/sqrt(128))*log2(e)
    } else {
        idx -= totQ;
        if (idx >= totK) return;
        buf = Kb; nheads = NKV; scale = 1.0f;
    }
    int d = idx & 63;
    int rem = idx >> 6;
    int hh = rem % nheads;
    int s = (rem / nheads) & (SS - 1);
    int bb = rem / (nheads * SS);
    size_t base = ((size_t)(bb * SS + s) * nheads + hh) * DD;
    float x0 = bf2f(buf[base + d]), x1 = bf2f(buf[base + d + 64]);
    float c = cosT[s * DD + d], sn = sinT[s * DD + d];
    buf[base + d]      = f2bf((x0 * c - x1 * sn) * scale);
    buf[base + d + 64] = f2bf((x0 * sn + x1 * c) * scale);
}

// ---------------------------------------------------------------------------
// P-exchange: 8 f32 P-values -> bf16 A-fragment (cvt_pk + shfl_xor(32)).
// ---------------------------------------------------------------------------
__device__ __forceinline__ short8 make_pa(float p0, float p1, float p2, float p3,
                                          float p4, float p5, float p6, float p7,
                                          int hi1)
{
    unsigned w0, w1, w2, w3;
    asm("v_cvt_pk_bf16_f32 %0, %1, %2" : "=v"(w0) : "v"(p0), "v"(p1));
    asm("v_cvt_pk_bf16_f32 %0, %1, %2" : "=v"(w1) : "v"(p2), "v"(p3));
    asm("v_cvt_pk_bf16_f32 %0, %1, %2" : "=v"(w2) : "v"(p4), "v"(p5));
    asm("v_cvt_pk_bf16_f32 %0, %1, %2" : "=v"(w3) : "v"(p6), "v"(p7));
    unsigned xw0 = (unsigned)__shfl_xor((int)w0, 32);
    unsigned xw1 = (unsigned)__shfl_xor((int)w1, 32);
    unsigned xw2 = (unsigned)__shfl_xor((int)w2, 32);
    unsigned xw3 = (unsigned)__shfl_xor((int)w3, 32);
    union { unsigned u[4]; short8 s; } cv;
    cv.u[0] = hi1 ? xw2 : w0;
    cv.u[1] = hi1 ? xw3 : w1;
    cv.u[2] = hi1 ? w2 : xw0;
    cv.u[3] = hi1 ? w3 : xw1;
    return cv.s;
}

// ---------------------------------------------------------------------------
// Flash attention v9 (verified): QBLK=256, 8 waves, 512 threads, all 512
// blocks resident, pair-balanced qt, XCD-chunk L2 locality.
// ---------------------------------------------------------------------------
__global__ __launch_bounds__(512, 2) void attn9_k(const u16* __restrict__ Qb,
                                                  const u16* __restrict__ Kb,
                                                  const u16* __restrict__ Vt,
                                                  u16* __restrict__ AO)
{
    const int wgid = blockIdx.x;
    const int k = wgid & 7;
    const int j = wgid >> 3;
    const int u = j & 31, v = j >> 5;
    const int qtb = u >> 3;
    const int qt = v ? 7 - qtb : qtb;
    const int h  = (k & 3) * 8 + (u & 7);
    const int b  = k >> 2;
    const int hkv = h >> 2;
    const int tid = threadIdx.x;
    const int w = tid >> 6, lane = tid & 63;
    const int l31 = lane & 31, hi1 = lane >> 5;
    const int qr0 = qt * 256 + w * 32;

    __shared__ u16 Kl[2][64 * 128];
    __shared__ u16 Vl[2][128 * 64];

    short8 qf[8];
    {
        const u16* qrow = Qb + ((size_t)(b * SS + qr0 + l31) * NH + h) * DD + hi1 * 8;
#pragma unroll
        for (int ks = 0; ks < 8; ++ks) qf[ks] = *(const short8*)(qrow + ks * 16);
    }

    const u16* kbase = Kb + ((size_t)b * SS * NKV + hkv) * DD;
    const u16* vbase = Vt + (size_t)(b * NKV + hkv) * DD * SS;

    f32x16 oacc[4] = {};
    float mreg = -INFINITY, lreg = 0.f;

    const int nkt = 4 * qt + 4;
    const int rk = lane >> 4, sk = lane & 15;
    const int rv = lane >> 3, sv = lane & 7;

#pragma unroll
    for (int i = 0; i < 2; ++i) {
        const int c = w * 2 + i;
        const int krow = c * 4 + rk;
        GLOAD16(kbase + (size_t)krow * (NKV * DD) + ((sk ^ (krow & 15)) * 8), &Kl[0][c * 512]);
        const int vrow = c * 8 + rv;
        GLOAD16(vbase + (size_t)vrow * SS + ((sv ^ (vrow & 7)) * 8), &Vl[0][c * 512]);
    }
    __syncthreads();

    int buf = 0;
    for (int kt = 0; kt < nkt; ++kt) {
        const int kv0 = kt * 64;
        if (kt + 1 < nkt) {
            const int kv1 = kv0 + 64;
#pragma unroll
            for (int i = 0; i < 2; ++i) {
                const int c = w * 2 + i;
                const int krow = c * 4 + rk;
                GLOAD16(kbase + (size_t)(kv1 + krow) * (NKV * DD) + ((sk ^ (krow & 15)) * 8),
                        &Kl[buf ^ 1][c * 512]);
                const int vrow = c * 8 + rv;
                GLOAD16(vbase + (size_t)vrow * SS + kv1 + ((sv ^ (vrow & 7)) * 8),
                        &Vl[buf ^ 1][c * 512]);
            }
        }

        if (kv0 <= qr0 + 31) {
            const u16* Kc = Kl[buf];
            const u16* Vc = Vl[buf];

            f32x16 s0 = {}, s1 = {};
            __builtin_amdgcn_s_setprio(1);
#pragma unroll
            for (int ks = 0; ks < 8; ++ks) {
                const int slot = (((2 * ks + hi1) ^ sk) * 8);
                short8 kf0 = *(const short8*)&Kc[l31 * 128 + slot];
                s0 = MFMA32(kf0, qf[ks], s0);
                short8 kf1 = *(const short8*)&Kc[(32 + l31) * 128 + slot];
                s1 = MFMA32(kf1, qf[ks], s1);
            }
            __builtin_amdgcn_s_setprio(0);

            const int qab = qr0 + l31;
            if (kv0 + 63 > qr0) {
#pragma unroll
                for (int r = 0; r < 16; ++r) {
                    const int off = (r & 3) + 8 * (r >> 2) + 4 * hi1;
                    if (kv0 + off > qab)      s0[r] = -INFINITY;
                    if (kv0 + 32 + off > qab) s1[r] = -INFINITY;
                }
            }
            float m0 = fmaxf(s0[0], s1[0]), m1 = fmaxf(s0[1], s1[1]);
            float m2 = fmaxf(s0[2], s1[2]), m3 = fmaxf(s0[3], s1[3]);
#pragma unroll
            for (int r = 4; r < 16; r += 4) {
                m0 = fmaxf(m0, fmaxf(s0[r],     s1[r]));
                m1 = fmaxf(m1, fmaxf(s0[r + 1], s1[r + 1]));
                m2 = fmaxf(m2, fmaxf(s0[r + 2], s1[r + 2]));
                m3 = fmaxf(m3, fmaxf(s0[r + 3], s1[r + 3]));
            }
            float mx = fmaxf(fmaxf(m0, m1), fmaxf(m2, m3));
            mx = fmaxf(mx, __shfl_xor(mx, 32));

            if (__any(mx > mreg + 8.0f)) {
                const float nm = fmaxf(mreg, mx);
                const float al = exp2f(mreg - nm);
                mreg = nm;
                lreg *= al;
#pragma unroll
                for (int r = 0; r < 16; ++r) {
                    const float ar = __shfl(al, (r & 3) + 8 * (r >> 2) + 4 * hi1);
#pragma unroll
                    for (int db = 0; db < 4; ++db) oacc[db][r] *= ar;
                }
            }

#pragma unroll
            for (int r = 0; r < 16; ++r) {
                s0[r] = exp2f(s0[r] - mreg);
                s1[r] = exp2f(s1[r] - mreg);
            }
            float sa = 0.f, sb = 0.f, sc_ = 0.f, sd = 0.f;
#pragma unroll
            for (int r = 0; r < 16; r += 4) {
                sa  += s0[r]     + s1[r];
                sb  += s0[r + 1] + s1[r + 1];
                sc_ += s0[r + 2] + s1[r + 2];
                sd  += s0[r + 3] + s1[r + 3];
            }
            lreg += (sa + sb) + (sc_ + sd);

            short8 pa0 = make_pa(s0[0], s0[1], s0[2],  s0[3],  s0[4],  s0[5],  s0[6],  s0[7],  hi1);
            short8 pa1 = make_pa(s0[8], s0[9], s0[10], s0[11], s0[12], s0[13], s0[14], s0[15], hi1);
            short8 pa2 = make_pa(s1[0], s1[1], s1[2],  s1[3],  s1[4],  s1[5],  s1[6],  s1[7],  hi1);
            short8 pa3 = make_pa(s1[8], s1[9], s1[10], s1[11], s1[12], s1[13], s1[14], s1[15], hi1);

            __builtin_amdgcn_s_setprio(1);
#pragma unroll
            for (int db = 0; db < 4; ++db) {
                const int vr = (db * 32 + l31) * 64;
                short8 vf0 = *(const short8*)&Vc[vr + (((0 + hi1) ^ sv) * 8)];
                oacc[db] = MFMA32(pa0, vf0, oacc[db]);
                short8 vf1 = *(const short8*)&Vc[vr + (((2 + hi1) ^ sv) * 8)];
                oacc[db] = MFMA32(pa1, vf1, oacc[db]);
                short8 vf2 = *(const short8*)&Vc[vr + (((4 + hi1) ^ sv) * 8)];
                oacc[db] = MFMA32(pa2, vf2, oacc[db]);
                short8 vf3 = *(const short8*)&Vc[vr + (((6 + hi1) ^ sv) * 8)];
                oacc[db] = MFMA32(pa3, vf3, oacc[db]);
            }
            __builtin_amdgcn_s_setprio(0);
        }
        __syncthreads();
        buf ^= 1;
    }

    const float lf = lreg + __shfl_xor(lreg, 32);
#pragma unroll
    for (int r = 0; r < 16; ++r) {
        const int qrw = (r & 3) + 8 * (r >> 2) + 4 * hi1;
        const float linv = 1.0f / __shfl(lf, qrw);
        u16* orow = AO + ((size_t)(b * SS + qr0 + qrw) * NH + h) * DD + l31;
#pragma unroll
        for (int db = 0; db < 4; ++db)
            orow[db * 32] = f2bf(oacc[db][r] * linv);
    }
}

// ===========================================================================
// FALLBACK (round-1 proven path, used only if ws_size is too small)
// ===========================================================================
template<bool A_BF16, bool C_F32>
__global__ __launch_bounds__(256) void gemm_k(const void* __restrict__ Ap,
                                              const float* __restrict__ Bp,
                                              void* __restrict__ Cp,
                                              int M, int N, int K)
{
    __shared__ u16 Asm[128 * 40];
    __shared__ u16 Bsm[128 * 40];
    const int tid  = threadIdx.x;
    const int lane = tid & 63, wid = tid >> 6;
    const int lo = lane & 15, hi = lane >> 4;
    const int wm = wid >> 1, wn = wid & 1;
    const int m0 = blockIdx.y * 128, n0 = blockIdx.x * 128;
    f32x4 acc[4][4] = {};
    const int nkt = K >> 5;
    for (int kt = 0; kt < nkt; ++kt) {
        const int k0 = kt << 5;
        __syncthreads();
        if constexpr (A_BF16) {
            const u16* A = (const u16*)Ap;
#pragma unroll
            for (int it = 0; it < 4; ++it) {
                int f = it * 256 + tid;
                int row = f >> 3, kg = (f & 7) * 4;
                us4 v = *(const us4*)(A + (size_t)(m0 + row) * K + k0 + kg);
#pragma unroll
                for (int j = 0; j < 4; ++j) Asm[row * 40 + kg + j] = v[j];
            }
        } else {
            const float* A = (const float*)Ap;
#pragma unroll
            for (int it = 0; it < 4; ++it) {
                int f = it * 256 + tid;
                int row = f >> 3, kg = (f & 7) * 4;
                f32x4 v = *(const f32x4*)(A + (size_t)(m0 + row) * K + k0 + kg);
#pragma unroll
                for (int j = 0; j < 4; ++j) Asm[row * 40 + kg + j] = f2bf(v[j]);
            }
        }
#pragma unroll
        for (int it = 0; it < 4; ++it) {
            int f = it * 256 + tid;
            int kr = f >> 5, cg = (f & 31) * 4;
            f32x4 v = *(const f32x4*)(Bp + (size_t)(k0 + kr) * N + n0 + cg);
#pragma unroll
            for (int j = 0; j < 4; ++j) Bsm[(cg + j) * 40 + kr] = f2bf(v[j]);
        }
        __syncthreads();
        short8 af[4], bfr[4];
#pragma unroll
        for (int i = 0; i < 4; ++i)
            af[i] = *(const short8*)&Asm[(wm * 64 + i * 16 + lo) * 40 + hi * 8];
#pragma unroll
        for (int j = 0; j < 4; ++j)
            bfr[j] = *(const short8*)&Bsm[(wn * 64 + j * 16 + lo) * 40 + hi * 8];
#pragma unroll
        for (int i = 0; i < 4; ++i)
#pragma unroll
            for (int j = 0; j < 4; ++j)
                acc[i][j] = MFMA16(af[i], bfr[j], acc[i][j]);
    }
#pragma unroll
    for (int i = 0; i < 4; ++i) {
        int gm = m0 + wm * 64 + i * 16 + hi * 4;
#pragma unroll
        for (int j = 0; j < 4; ++j) {
            int gn = n0 + wn * 64 + j * 16 + lo;
#pragma unroll
            for (int r = 0; r < 4; ++r) {
                if constexpr (C_F32)
                    ((float*)Cp)[(size_t)(gm + r) * N + gn] = acc[i][j][r];
                else
                    ((u16*)Cp)[(size_t)(gm + r) * N + gn] = f2bf(acc[i][j][r]);
            }
        }
    }
}

__global__ __launch_bounds__(64) void attn_k(const u16* __restrict__ Qb,
                                             const u16* __restrict__ Kb,
                                             const u16* __restrict__ Vb,
                                             u16* __restrict__ AO)
{
    const int blk = blockIdx.x;
    const int qt = blk & (SS / 16 - 1);
    const int h  = (blk >> 7) & (NH - 1);
    const int b  = blk >> 12;
    const int hkv = h >> 2;
    const int lane = threadIdx.x;
    const int lo = lane & 15, hi = lane >> 4;
    const int qbase = qt * 16;
    __shared__ float sc[16][32];
    __shared__ u16 vt[128 * 40];
    short8 qf[4];
    const u16* qrow = Qb + ((size_t)(b * SS + qbase + lo) * NH + h) * DD;
#pragma unroll
    for (int c = 0; c < 4; ++c) qf[c] = *(const short8*)(qrow + c * 32 + hi * 8);
    f32x4 oacc[8] = {};
    float m[4] = {-INFINITY, -INFINITY, -INFINITY, -INFINITY};
    float l[4] = {0.f, 0.f, 0.f, 0.f};
    const int nkt = (qbase + 16 + 31) >> 5;
    for (int kt = 0; kt < nkt; ++kt) {
        const int kv0 = kt << 5;
        f32x4 s0 = {}, s1 = {};
        const u16* kb0 = Kb + ((size_t)(b * SS + kv0) * NKV + hkv) * DD;
#pragma unroll
        for (int c = 0; c < 4; ++c) {
            short8 k0f = *(const short8*)(kb0 + (size_t)lo * (NKV * DD) + c * 32 + hi * 8);
            short8 k1f = *(const short8*)(kb0 + (size_t)(lo + 16) * (NKV * DD) + c * 32 + hi * 8);
            s0 = MFMA16(qf[c], k0f, s0);
            s1 = MFMA16(qf[c], k1f, s1);
        }
#pragma unroll
        for (int i = 0; i < 8; ++i) {
            int g = i * 64 + lane;
            int row = g >> 4, dg = (g & 15) * 8;
            short8 vv = *(const short8*)(Vb + ((size_t)(b * SS + kv0 + row) * NKV + hkv) * DD + dg);
#pragma unroll
            for (int j = 0; j < 8; ++j) vt[(dg + j) * 40 + row] = (u16)vv[j];
        }
        float alpha[4];
#pragma unroll
        for (int r = 0; r < 4; ++r) {
            int qrowi = qbase + hi * 4 + r;
            float v0 = s0[r]; if (kv0 + lo > qrowi)      v0 = -INFINITY;
            float v1 = s1[r]; if (kv0 + 16 + lo > qrowi) v1 = -INFINITY;
            float mx = fmaxf(v0, v1);
#pragma unroll
            for (int off = 1; off < 16; off <<= 1) mx = fmaxf(mx, __shfl_xor(mx, off, 64));
            float nm = fmaxf(m[r], mx);
            float a = __expf(m[r] - nm);
            v0 = __expf(v0 - nm);
            v1 = __expf(v1 - nm);
            float ps = v0 + v1;
#pragma unroll
            for (int off = 1; off < 16; off <<= 1) ps += __shfl_xor(ps, off, 64);
            l[r] = l[r] * a + ps;
            m[r] = nm;
            alpha[r] = a;
            sc[hi * 4 + r][lo] = v0;
            sc[hi * 4 + r][16 + lo] = v1;
        }
#pragma unroll
        for (int n = 0; n < 8; ++n)
#pragma unroll
            for (int r = 0; r < 4; ++r) oacc[n][r] *= alpha[r];
        __syncthreads();
        f32x4 p0 = *(const f32x4*)&sc[lo][hi * 8];
        f32x4 p1 = *(const f32x4*)&sc[lo][hi * 8 + 4];
        short8 pf;
#pragma unroll
        for (int j = 0; j < 4; ++j) {
            pf[j]     = (short)f2bf(p0[j]);
            pf[4 + j] = (short)f2bf(p1[j]);
        }
#pragma unroll
        for (int n = 0; n < 8; ++n) {
            short8 vf = *(const short8*)&vt[(n * 16 + lo) * 40 + hi * 8];
            oacc[n] = MFMA16(pf, vf, oacc[n]);
        }
        __syncthreads();
    }
#pragma unroll
    for (int n = 0; n < 8; ++n) {
#pragma unroll
        for (int r = 0; r < 4; ++r) {
            size_t idx = ((size_t)(b * SS + qbase + hi * 4 + r) * NH + h) * DD + n * 16 + lo;
            AO[idx] = f2bf(oacc[n][r] / l[r]);
        }
    }
}

// ---------------------------------------------------------------------------
extern "C" void kernel_launch(void* const* d_in, const int* in_sizes, int n_in,
                              void* d_out, int out_size, void* d_ws, size_t ws_size,
                              hipStream_t stream) {
    const float* hs   = (const float*)d_in[0];
    const float* sinT = (const float*)d_in[1];
    const float* cosT = (const float*)d_in[2];
    const float* Wq   = (const float*)d_in[3];
    const float* Wk   = (const float*)d_in[4];
    const float* Wv   = (const float*)d_in[5];
    const float* Wo   = (const float*)d_in[6];
    float* out = (float*)d_out;
    const int M = BB * SS;
    u16* ws = (u16*)d_ws;

    const size_t NEED = 109051904;  // bytes (54,525,952 u16)
    if (ws_size >= NEED) {
        u16* Qb   = ws;                 // [0, 16777216)
        u16* Kb   = ws + 16777216;      // [16777216, 20971520)
        u16* Vt   = ws + 25165824;      // [25165824, 29360128)
        u16* Wcat = ws + 29360128;      // [29360128, 41943040)  6144x2048
        u16* hsb  = ws + 41943040;      // [41943040, 50331648)
        u16* Wot  = Wcat;               // reuse after QKV gemm
        u16* AO   = ws + 37748736;      // [37748736, 54525952)  after Wot transpose

        cvt_k<<<4096, 256, 0, stream>>>(hs, hsb, (M * HID) / 8);
        // Wcat rows: [0,4096)=Wq^T, [4096,5120)=Wk^T, [5120,6144)=Wv^T
        tw_k<<<dim3(4096 / 32, 2048 / 32), 256, 0, stream>>>(Wq, Wcat, HID, NH * DD);
        tw_k<<<dim3(1024 / 32, 2048 / 32), 256, 0, stream>>>(Wk, Wcat + (size_t)4096 * 2048, HID, NKV * DD);
        tw_k<<<dim3(1024 / 32, 2048 / 32), 256, 0, stream>>>(Wv, Wcat + (size_t)5120 * 2048, HID, NKV * DD);

        // fused QKV projection (256^2 deep pipeline, V written to Vt^T)
        gemm8qkv_k<<<384, 512, 0, stream>>>(hsb, Wcat, Qb, Kb, Vt);

        // RoPE on Q (scaled) and K in one launch
        {
            const int tot = BB * SS * (NH + NKV) * 64;
            rope2_k<<<(tot + 255) / 256, 256, 0, stream>>>(Qb, Kb, cosT, sinT);
        }
        tw_k<<<dim3(2048 / 32, 4096 / 32), 256, 0, stream>>>(Wo, Wot, NH * DD, HID);

        attn9_k<<<SS / 256 * NH * BB, 512, 0, stream>>>(Qb, Kb, Vt, AO);

        // output projection (proven 2-phase 128^2, 512 blocks)
        gemm2s_k<true><<<512, 256, 0, stream>>>(AO, Wot, out, M, HID, NH * DD, HID / 128);
    } else {
        u16* Qb   = ws;
        u16* Kbuf = Qb   + (size_t)BB * SS * NH * DD;
        u16* Vbuf = Kbuf + (size_t)BB * SS * NKV * DD;
        u16* AO   = Vbuf + (size_t)BB * SS * NKV * DD;

        gemm_k<false, false><<<dim3((NH * DD) / 128, M / 128), 256, 0, stream>>>(hs, Wq, Qb, M, NH * DD, HID);
        gemm_k<false, false><<<dim3((NKV * DD) / 128, M / 128), 256, 0, stream>>>(hs, Wk, Kbuf, M, NKV * DD, HID);
        gemm_k<false, false><<<dim3((NKV * DD) / 128, M / 128), 256, 0, stream>>>(hs, Wv, Vbuf, M, NKV * DD, HID);
        {
            const int totQ = BB * SS * NH * 64;
            rope2_k<<<(totQ + BB * SS * NKV * 64 + 255) / 256, 256, 0, stream>>>(Qb, Kbuf, cosT, sinT);
        }
        attn_k<<<BB * NH * (SS / 16), 64, 0, stream>>>(Qb, Kbuf, Vbuf, AO);
        gemm_k<true, true><<<dim3(HID / 128, M / 128), 256, 0, stream>>>(AO, Wo, out, M, HID, NH * DD);
    }
}